// Round 1
// baseline (4184.897 us; speedup 1.0000x reference)
//
#include <hip/hip_runtime.h>
#include <hip/hip_bf16.h>

#define N_NODES 10000
#define N_EDGES 160000

// ---------------------------------------------------------------------------
// Generic fp32 GEMM: C[N,M] = act(A[N,K] @ W[M,K]^T + bias)
// A row-major [N,K], W row-major [M,K]. All K,M multiples of 4.
// Tile 64x64, BK=32, 256 threads, 4x4 micro-tile per thread.
// ---------------------------------------------------------------------------
#define BM 64
#define BN 64
#define BKK 32

__global__ __launch_bounds__(256) void k_gemm(
    const float* __restrict__ A, const float* __restrict__ W,
    const float* __restrict__ bias, float* __restrict__ C,
    int N, int K, int M, int act, float slope)
{
    __shared__ float As[BKK][BM + 4];  // +4 pad: row stride 68 floats = 272B (16B mult)
    __shared__ float Bs[BKK][BN + 4];

    const int tid = threadIdx.x;
    const int row0 = blockIdx.y * BM;
    const int col0 = blockIdx.x * BN;
    const int tx = tid & 15;        // col quad
    const int ty = tid >> 4;        // row quad

    float acc[4][4] = {};

    const int nk = (K + BKK - 1) / BKK;
    for (int t = 0; t < nk; ++t) {
        const int k0 = t * BKK;
        // stage A tile (64 rows x 32 k) as As[k][r]
        #pragma unroll
        for (int v = tid; v < 512; v += 256) {
            const int r = v >> 3, kq = (v & 7) << 2;
            float4 val = make_float4(0.f, 0.f, 0.f, 0.f);
            const int gr = row0 + r, gk = k0 + kq;
            if (gr < N && gk < K)
                val = *reinterpret_cast<const float4*>(&A[(size_t)gr * K + gk]);
            As[kq + 0][r] = val.x; As[kq + 1][r] = val.y;
            As[kq + 2][r] = val.z; As[kq + 3][r] = val.w;
        }
        // stage W tile (64 rows x 32 k) as Bs[k][r]
        #pragma unroll
        for (int v = tid; v < 512; v += 256) {
            const int r = v >> 3, kq = (v & 7) << 2;
            float4 val = make_float4(0.f, 0.f, 0.f, 0.f);
            const int gr = col0 + r, gk = k0 + kq;
            if (gr < M && gk < K)
                val = *reinterpret_cast<const float4*>(&W[(size_t)gr * K + gk]);
            Bs[kq + 0][r] = val.x; Bs[kq + 1][r] = val.y;
            Bs[kq + 2][r] = val.z; Bs[kq + 3][r] = val.w;
        }
        __syncthreads();
        #pragma unroll 8
        for (int k = 0; k < BKK; ++k) {
            const float4 a = *reinterpret_cast<const float4*>(&As[k][ty << 2]);
            const float4 b = *reinterpret_cast<const float4*>(&Bs[k][tx << 2]);
            acc[0][0] += a.x * b.x; acc[0][1] += a.x * b.y; acc[0][2] += a.x * b.z; acc[0][3] += a.x * b.w;
            acc[1][0] += a.y * b.x; acc[1][1] += a.y * b.y; acc[1][2] += a.y * b.z; acc[1][3] += a.y * b.w;
            acc[2][0] += a.z * b.x; acc[2][1] += a.z * b.y; acc[2][2] += a.z * b.z; acc[2][3] += a.z * b.w;
            acc[3][0] += a.w * b.x; acc[3][1] += a.w * b.y; acc[3][2] += a.w * b.z; acc[3][3] += a.w * b.w;
        }
        __syncthreads();
    }

    const int gc = col0 + (tx << 2);
    if (gc >= M) return;
    float4 bv = make_float4(0.f, 0.f, 0.f, 0.f);
    if (bias) bv = *reinterpret_cast<const float4*>(&bias[gc]);
    #pragma unroll
    for (int i = 0; i < 4; ++i) {
        const int gr = row0 + (ty << 2) + i;
        if (gr >= N) continue;
        float4 o = make_float4(acc[i][0] + bv.x, acc[i][1] + bv.y,
                               acc[i][2] + bv.z, acc[i][3] + bv.w);
        if (act) {
            o.x = o.x >= 0.f ? o.x : slope * o.x;
            o.y = o.y >= 0.f ? o.y : slope * o.y;
            o.z = o.z >= 0.f ? o.z : slope * o.z;
            o.w = o.w >= 0.f ? o.w : slope * o.w;
        }
        *reinterpret_cast<float4*>(&C[(size_t)gr * M + gc]) = o;
    }
}

// ---------------------------------------------------------------------------
// CSR build: histogram, single-block exclusive scan, fill (src + edge weights)
// ---------------------------------------------------------------------------
__global__ void k_hist(const int* __restrict__ dst, int E, int* __restrict__ cnt)
{
    const int e = blockIdx.x * blockDim.x + threadIdx.x;
    if (e < E) atomicAdd(&cnt[dst[e]], 1);
}

__global__ __launch_bounds__(256) void k_scan(const int* __restrict__ cnt,
                                              int* __restrict__ rs, int n)
{
    __shared__ int sums[256];
    const int tid = threadIdx.x;
    const int T = (n + 255) / 256;
    const int base = tid * T;
    int s = 0;
    for (int i = 0; i < T; ++i) { const int idx = base + i; if (idx < n) s += cnt[idx]; }
    sums[tid] = s;
    __syncthreads();
    for (int o = 1; o < 256; o <<= 1) {
        const int v = (tid >= o) ? sums[tid - o] : 0;
        __syncthreads();
        sums[tid] += v;
        __syncthreads();
    }
    int run = (tid == 0) ? 0 : sums[tid - 1];
    for (int i = 0; i < T; ++i) {
        const int idx = base + i;
        if (idx < n) { rs[idx] = run; run += cnt[idx]; }
    }
    if (tid == 255) rs[n] = sums[255];
}

__global__ void k_fill(const int* __restrict__ src, const int* __restrict__ dst,
                       const float* __restrict__ ew, int E,
                       const int* __restrict__ rs, int* __restrict__ cur,
                       int* __restrict__ csrc, float* __restrict__ cew0,
                       float* __restrict__ cew1)
{
    const int e = blockIdx.x * blockDim.x + threadIdx.x;
    if (e >= E) return;
    const int d = dst[e];
    const int pos = rs[d] + atomicAdd(&cur[d], 1);
    csrc[pos] = src[e];
    cew0[pos] = ew[2 * e];
    cew1[pos] = ew[2 * e + 1];
}

// ---------------------------------------------------------------------------
// za_src[n] = dot(Z[n,:], wa[0:K]); za_dst[n] = dot(Z[n,:], wa[K:2K])
// one wave per node
// ---------------------------------------------------------------------------
__global__ __launch_bounds__(256) void k_dotwa(
    const float* __restrict__ Z, const float* __restrict__ wa, int K, int N,
    float* __restrict__ za_s, float* __restrict__ za_d)
{
    const int lane = threadIdx.x & 63;
    const int node = blockIdx.x * 4 + (threadIdx.x >> 6);
    if (node >= N) return;
    const float* zr = Z + (size_t)node * K;
    float s = 0.f, d = 0.f;
    for (int k = lane; k < K; k += 64) {
        const float zv = zr[k];
        s += zv * wa[k];
        d += zv * wa[K + k];
    }
    #pragma unroll
    for (int o = 32; o; o >>= 1) { s += __shfl_xor(s, o); d += __shfl_xor(d, o); }
    if (lane == 0) { za_s[node] = s; za_d[node] = d; }
}

// replicate-pad attention term collapses to two scalar sums of the Wa tail
__global__ __launch_bounds__(256) void k_wasums(const float* __restrict__ wa,
                                                int out, float* __restrict__ sums)
{
    __shared__ float red[256];
    const int tid = threadIdx.x;
    const int half = out >> 1;
    const float* t0 = wa + 2 * out;
    float s0 = 0.f, s1 = 0.f;
    for (int i = tid; i < half; i += 256) { s0 += t0[i]; s1 += t0[half + i]; }
    red[tid] = s0; __syncthreads();
    for (int o = 128; o; o >>= 1) { if (tid < o) red[tid] += red[tid + o]; __syncthreads(); }
    if (tid == 0) sums[0] = red[0];
    __syncthreads();
    red[tid] = s1; __syncthreads();
    for (int o = 128; o; o >>= 1) { if (tid < o) red[tid] += red[tid + o]; __syncthreads(); }
    if (tid == 0) sums[1] = red[0];
}

// ---------------------------------------------------------------------------
// Per-dst-node edge softmax over CSR segment; writes alpha into EV (CSR order)
// one wave per node; 3 passes, shfl reductions, no atomics
// ---------------------------------------------------------------------------
__global__ __launch_bounds__(256) void k_attn(
    const int* __restrict__ rs, const int* __restrict__ csrc,
    const float* __restrict__ cew0, const float* __restrict__ cew1,
    const float* __restrict__ za_s, const float* __restrict__ za_d,
    const float* __restrict__ ewsums, float* __restrict__ EV, int N)
{
    const int lane = threadIdx.x & 63;
    const int n = blockIdx.x * 4 + (threadIdx.x >> 6);
    if (n >= N) return;
    const int s0 = rs[n];
    const int cnt = rs[n + 1] - s0;
    if (cnt == 0) return;
    const float zd = za_d[n];
    float w0 = 0.f, w1 = 0.f;
    if (ewsums) { w0 = ewsums[0]; w1 = ewsums[1]; }

    float mx = -INFINITY;
    for (int i = lane; i < cnt; i += 64) {
        float ev = za_s[csrc[s0 + i]] + zd + cew0[s0 + i] * w0 + cew1[s0 + i] * w1;
        ev = ev >= 0.f ? ev : 0.01f * ev;   // leaky_relu(0.01)
        EV[s0 + i] = ev;
        mx = fmaxf(mx, ev);
    }
    #pragma unroll
    for (int o = 32; o; o >>= 1) mx = fmaxf(mx, __shfl_xor(mx, o));

    float sum = 0.f;
    for (int i = lane; i < cnt; i += 64) {
        const float ex = expf(EV[s0 + i] - mx);
        EV[s0 + i] = ex;
        sum += ex;
    }
    #pragma unroll
    for (int o = 32; o; o >>= 1) sum += __shfl_xor(sum, o);

    for (int i = lane; i < cnt; i += 64) EV[s0 + i] /= sum;
}

// ---------------------------------------------------------------------------
// Aggregate + GAT epilogue: Out[n, coff+f] = h + relu(deg>0 ? h_s + agg : h)
// one wave per (node, 64-feature chunk); non-atomic owned writes
// ---------------------------------------------------------------------------
__global__ __launch_bounds__(256) void k_aggfin(
    const int* __restrict__ rs, const int* __restrict__ csrc,
    const float* __restrict__ EV, const float* __restrict__ Z,
    const float* __restrict__ HS, const float* __restrict__ Hin,
    float* __restrict__ Out, int N, int out, int ldo, int coff)
{
    const int lane = threadIdx.x & 63;
    const int n = blockIdx.x * 4 + (threadIdx.x >> 6);
    if (n >= N) return;
    const int f = blockIdx.y * 64 + lane;
    if (f >= out) return;
    const int s0 = rs[n];
    const int cnt = rs[n + 1] - s0;
    float acc = 0.f;
    for (int i = 0; i < cnt; ++i) {
        const float a = EV[s0 + i];
        const int sn = csrc[s0 + i];
        acc += a * Z[(size_t)sn * out + f];
    }
    const float hv = Hin[(size_t)n * out + f];
    const float hn = (cnt > 0) ? (HS[(size_t)n * out + f] + acc) : hv;
    Out[(size_t)n * ldo + coff + f] = hv + fmaxf(hn, 0.f);
}

// ---------------------------------------------------------------------------
// column-block copy (float4): dst[r, d_off + c] = src[r, c], c < cols
// ---------------------------------------------------------------------------
__global__ void k_copy4(const float* __restrict__ src, int s_ld,
                        float* __restrict__ dst, int d_ld, int d_off,
                        int cols, int N)
{
    const int q = cols >> 2;
    const int idx = blockIdx.x * blockDim.x + threadIdx.x;
    if (idx >= N * q) return;
    const int r = idx / q;
    const int c = (idx % q) << 2;
    *reinterpret_cast<float4*>(&dst[(size_t)r * d_ld + d_off + c]) =
        *reinterpret_cast<const float4*>(&src[(size_t)r * s_ld + c]);
}

// z = mu + exp(0.5*log_var) * eps
__global__ void k_reparam(const float* __restrict__ mu, const float* __restrict__ lv,
                          const float* __restrict__ eps, float* __restrict__ z, int total)
{
    const int i = blockIdx.x * blockDim.x + threadIdx.x;
    if (i < total) z[i] = mu[i] + expf(0.5f * lv[i]) * eps[i];
}

// ---------------------------------------------------------------------------
// host side
// ---------------------------------------------------------------------------
static inline void gemm(hipStream_t st, const float* A, const float* W,
                        const float* bias, float* C, int N, int K, int M,
                        int act, float slope)
{
    dim3 g((M + BN - 1) / BN, (N + BM - 1) / BM);
    k_gemm<<<g, 256, 0, st>>>(A, W, bias, C, N, K, M, act, slope);
}

struct CsrPtrs {
    const int* rs; const int* csrc; const float* cew0; const float* cew1;
};

static void gat_layer(hipStream_t st, const float* Hin, int dim,
                      const float* Ws, const float* Wf, const float* Wa, bool has_ew,
                      float* Zb, float* HSb, float* za_s, float* za_d, float* wa_sums,
                      const CsrPtrs& csr, float* EV, float* Out, int ldo, int coff)
{
    gemm(st, Hin, Wf, nullptr, Zb, N_NODES, dim, dim, 0, 0.f);   // z = h @ Wf^T
    gemm(st, Hin, Ws, nullptr, HSb, N_NODES, dim, dim, 0, 0.f);  // h_s = h @ Ws^T
    k_dotwa<<<N_NODES / 4, 256, 0, st>>>(Zb, Wa, dim, N_NODES, za_s, za_d);
    const float* es = nullptr;
    if (has_ew) {
        k_wasums<<<1, 256, 0, st>>>(Wa, dim, wa_sums);
        es = wa_sums;
    }
    k_attn<<<N_NODES / 4, 256, 0, st>>>(csr.rs, csr.csrc, csr.cew0, csr.cew1,
                                        za_s, za_d, es, EV, N_NODES);
    dim3 ga(N_NODES / 4, (dim + 63) / 64);
    k_aggfin<<<ga, 256, 0, st>>>(csr.rs, csr.csrc, EV, Zb, HSb, Hin, Out,
                                 N_NODES, dim, ldo, coff);
}

static inline void copy4(hipStream_t st, const float* src, int s_ld,
                         float* dst, int d_ld, int d_off, int cols)
{
    const int total = N_NODES * (cols >> 2);
    k_copy4<<<(total + 255) / 256, 256, 0, st>>>(src, s_ld, dst, d_ld, d_off, cols, N_NODES);
}

extern "C" void kernel_launch(void* const* d_in, const int* in_sizes, int n_in,
                              void* d_out, int out_size, void* d_ws, size_t ws_size,
                              hipStream_t stream)
{
    // ---- inputs (setup_inputs dict order) ----
    const float* feats    = (const float*)d_in[0];
    const float* gt       = (const float*)d_in[1];
    const float* maps_emb = (const float*)d_in[2];
    const float* e_w      = (const float*)d_in[3];
    const float* eps      = (const float*)d_in[4];
    const int*   src      = (const int*)d_in[5];
    const int*   dst      = (const int*)d_in[6];
    const float* emb_W    = (const float*)d_in[7];
    const float* emb_b    = (const float*)d_in[8];
    const float* enc1_Ws  = (const float*)d_in[9];
    const float* enc1_Wf  = (const float*)d_in[10];
    const float* enc1_Wa  = (const float*)d_in[11];
    const float* enc2_Ws  = (const float*)d_in[12];
    const float* enc2_Wf  = (const float*)d_in[13];
    const float* enc2_Wa  = (const float*)d_in[14];
    const float* encmlp_W = (const float*)d_in[15];
    const float* encmlp_b = (const float*)d_in[16];
    const float* mu_W     = (const float*)d_in[17];
    const float* mu_b     = (const float*)d_in[18];
    const float* lv_W     = (const float*)d_in[19];
    const float* lv_b     = (const float*)d_in[20];
    const float* dec1_Ws  = (const float*)d_in[21];
    const float* dec1_Wf  = (const float*)d_in[22];
    const float* dec1_Wa  = (const float*)d_in[23];
    const float* dec2_Ws  = (const float*)d_in[24];
    const float* dec2_Wf  = (const float*)d_in[25];
    const float* dec2_Wa  = (const float*)d_in[26];
    const float* dec0_W   = (const float*)d_in[27];
    const float* dec0_b   = (const float*)d_in[28];
    const float* dec1o_W  = (const float*)d_in[29];
    const float* dec1o_b  = (const float*)d_in[30];

    // ---- workspace layout (256B aligned slabs) ----
    char* wp = (char*)d_ws;
    size_t off = 0;
    auto alloc_f = [&](size_t nfloats) -> float* {
        float* p = (float*)(wp + off);
        off = (off + nfloats * sizeof(float) + 255) & ~(size_t)255;
        return p;
    };
    auto alloc_i = [&](size_t nints) -> int* {
        int* p = (int*)(wp + off);
        off = (off + nints * sizeof(int) + 255) & ~(size_t)255;
        return p;
    };

    float* A_CAT   = alloc_f((size_t)N_NODES * 1120);
    float* OUTB    = alloc_f((size_t)N_NODES * 1120);
    float* Zb      = alloc_f((size_t)N_NODES * 1088);
    float* HSb     = alloc_f((size_t)N_NODES * 1088);
    float* h_emb   = alloc_f((size_t)N_NODES * 256);
    float* zlat    = alloc_f((size_t)N_NODES * 32);
    float* za_s    = alloc_f(N_NODES);
    float* za_d    = alloc_f(N_NODES);
    float* EV      = alloc_f(N_EDGES);
    float* cew0    = alloc_f(N_EDGES);
    float* cew1    = alloc_f(N_EDGES);
    float* wa_sums = alloc_f(64);
    int*   cnt     = alloc_i(N_NODES);
    int*   rs      = alloc_i(N_NODES + 1);
    int*   csrc    = alloc_i(N_EDGES);
    (void)ws_size; (void)in_sizes; (void)n_in; (void)out_size;

    CsrPtrs csr{rs, csrc, cew0, cew1};

    // ---- CSR build (dst is constant input; rebuilt every launch) ----
    hipMemsetAsync(cnt, 0, N_NODES * sizeof(int), stream);
    k_hist<<<(N_EDGES + 255) / 256, 256, 0, stream>>>(dst, N_EDGES, cnt);
    k_scan<<<1, 256, 0, stream>>>(cnt, rs, N_NODES);
    hipMemsetAsync(cnt, 0, N_NODES * sizeof(int), stream);
    k_fill<<<(N_EDGES + 255) / 256, 256, 0, stream>>>(src, dst, e_w, N_EDGES,
                                                      rs, cnt, csrc, cew0, cew1);

    // ---- embedding ----
    gemm(stream, feats, emb_W, emb_b, h_emb, N_NODES, 24, 256, 0, 0.f);

    // ---- encoder input: [maps_emb | h_emb | gt]  (536) ----
    copy4(stream, maps_emb, 256, A_CAT, 536, 0, 256);
    copy4(stream, h_emb, 256, A_CAT, 536, 256, 256);
    copy4(stream, gt, 24, A_CAT, 536, 512, 24);

    // ---- encoder GAT layer 1 (2 heads, att_ew) -> OUTB [N,1072] ----
    gat_layer(stream, A_CAT, 536, enc1_Ws, enc1_Wf, enc1_Wa, true,
              Zb, HSb, za_s, za_d, wa_sums, csr, EV, OUTB, 1072, 0);
    gat_layer(stream, A_CAT, 536, enc1_Ws + 536 * 536, enc1_Wf + 536 * 536,
              enc1_Wa + 3 * 536, true,
              Zb, HSb, za_s, za_d, wa_sums, csr, EV, OUTB, 1072, 536);

    // ---- encoder GAT layer 2 (1 head, att_ew) -> A_CAT [N,1072] ----
    gat_layer(stream, OUTB, 1072, enc2_Ws, enc2_Wf, enc2_Wa, true,
              Zb, HSb, za_s, za_d, wa_sums, csr, EV, A_CAT, 1072, 0);

    // ---- MLP encoder + reparameterize ----
    copy4(stream, A_CAT, 1072, OUTB, 1096, 0, 1072);   // he = [h | gt]
    copy4(stream, gt, 24, OUTB, 1096, 1072, 24);
    gemm(stream, OUTB, encmlp_W, encmlp_b, Zb, N_NODES, 1096, 548, 1, 0.01f);
    float* mu = HSb;
    float* lv = HSb + (size_t)N_NODES * 32;
    gemm(stream, Zb, mu_W, mu_b, mu, N_NODES, 548, 32, 0, 0.f);
    gemm(stream, Zb, lv_W, lv_b, lv, N_NODES, 548, 32, 0, 0.f);
    k_reparam<<<(N_NODES * 32 + 255) / 256, 256, 0, stream>>>(mu, lv, eps, zlat,
                                                              N_NODES * 32);

    // ---- decoder input: [maps_emb | h_emb | z]  (544) ----
    copy4(stream, maps_emb, 256, A_CAT, 544, 0, 256);
    copy4(stream, h_emb, 256, A_CAT, 544, 256, 256);
    copy4(stream, zlat, 32, A_CAT, 544, 512, 32);

    // ---- decoder GAT layer 1 (2 heads, no ew) -> OUTB [N,1088] ----
    gat_layer(stream, A_CAT, 544, dec1_Ws, dec1_Wf, dec1_Wa, false,
              Zb, HSb, za_s, za_d, wa_sums, csr, EV, OUTB, 1088, 0);
    gat_layer(stream, A_CAT, 544, dec1_Ws + 544 * 544, dec1_Wf + 544 * 544,
              dec1_Wa + 2 * 544, false,
              Zb, HSb, za_s, za_d, wa_sums, csr, EV, OUTB, 1088, 544);

    // ---- decoder GAT layer 2 (1 head, no ew) -> A_CAT [N,1088] ----
    gat_layer(stream, OUTB, 1088, dec2_Ws, dec2_Wf, dec2_Wa, false,
              Zb, HSb, za_s, za_d, wa_sums, csr, EV, A_CAT, 1088, 0);

    // ---- MLP decoder ----
    copy4(stream, A_CAT, 1088, OUTB, 1120, 0, 1088);   // [hd | z]
    copy4(stream, zlat, 32, OUTB, 1120, 1088, 32);
    gemm(stream, OUTB, dec0_W, dec0_b, Zb, N_NODES, 1120, 544, 1, 0.02f);
    gemm(stream, Zb, dec1o_W, dec1o_b, (float*)d_out, N_NODES, 544, 24, 0, 0.f);
}

// Round 2
// 2459.072 us; speedup vs baseline: 1.7018x; 1.7018x over previous
//
#include <hip/hip_runtime.h>
#include <hip/hip_bf16.h>

#define N_NODES 10000
#define N_EDGES 160000

typedef __attribute__((ext_vector_type(8))) short bf16x8;
typedef __attribute__((ext_vector_type(4))) float f32x4;
typedef __attribute__((ext_vector_type(4))) unsigned short us4v;
typedef unsigned short ushort_t;

// ---------------------------------------------------------------------------
// fp32 -> (hi,lo) bf16 split with K zero-padding to Kp. 4 elems/thread.
// ---------------------------------------------------------------------------
__device__ __forceinline__ ushort_t f2bf(float x) {
    union { float f; unsigned u; } c; c.f = x;
    unsigned u = c.u;
    u += 0x7fffu + ((u >> 16) & 1u);       // RNE
    return (ushort_t)(u >> 16);
}
__device__ __forceinline__ float bf2f(ushort_t b) {
    union { unsigned u; float f; } c; c.u = ((unsigned)b) << 16;
    return c.f;
}

__global__ __launch_bounds__(256) void k_split(
    const float* __restrict__ src, int R, int K, int Kp,
    ushort_t* __restrict__ oh, ushort_t* __restrict__ ol, int row_off)
{
    const int q = Kp >> 2;
    const int idx = blockIdx.x * 256 + threadIdx.x;
    if (idx >= R * q) return;
    const int r = idx / q;
    const int k = (idx - r * q) << 2;
    float4 v = make_float4(0.f, 0.f, 0.f, 0.f);
    if (k < K) v = *reinterpret_cast<const float4*>(&src[(size_t)r * K + k]);
    float vv[4] = {v.x, v.y, v.z, v.w};
    us4v h, l;
    #pragma unroll
    for (int j = 0; j < 4; ++j) {
        const ushort_t hb = f2bf(vv[j]);
        h[j] = hb;
        l[j] = f2bf(vv[j] - bf2f(hb));
    }
    const size_t o = (size_t)(r + row_off) * Kp + k;
    *reinterpret_cast<us4v*>(&oh[o]) = h;
    *reinterpret_cast<us4v*>(&ol[o]) = l;
}

// ---------------------------------------------------------------------------
// bf16 split-MFMA GEMM: C[N,M] = act( (Ah+Al)[N,Kp] @ ((Wh+Wl)[M,Kp])^T + b )
// computed as Ah@Wh + Ah@Wl + Al@Wh. 128x128 tile, BK=64, 4 waves,
// mfma_f32_16x16x32_bf16, global_load_lds staging, XOR chunk swizzle.
// 2-segment C-write: cols<M1 -> C0 (+bias0), cols>=M1 -> C1 (+bias1).
// ---------------------------------------------------------------------------
__global__ __launch_bounds__(256) void k_mgemm(
    const ushort_t* __restrict__ Ah, const ushort_t* __restrict__ Al,
    const ushort_t* __restrict__ Wh, const ushort_t* __restrict__ Wl,
    const float* __restrict__ bias0, const float* __restrict__ bias1,
    float* __restrict__ C0, int ld0, int M1,
    float* __restrict__ C1, int ld1,
    int Nr, int Kp, int Mc, int act, float slope)
{
    __shared__ ushort_t As[128 * 64];
    __shared__ ushort_t Bs[128 * 64];

    const int tid = threadIdx.x;
    const int w = tid >> 6, l = tid & 63;
    const int wr = w >> 1, wc = w & 1;
    const int row0 = blockIdx.y * 128, col0 = blockIdx.x * 128;

    // staging lane constants: lane l deposits at LDS row (base+l>>3), chunk l&7.
    // We pre-swizzle the GLOBAL chunk so LDS(row,c') holds global chunk c'^(row&7).
    const int rsub = l >> 3;
    const int cg = (((l & 7) ^ (rsub & 7)) << 3);       // element offset in row
    // fragment-read lane constants
    const int fr = l & 15, fq = l >> 4;
    const int ca0 = (((0 * 4 + fq) ^ (l & 7)) << 3);    // ks=0 swizzled chunk
    const int ca1 = (((1 * 4 + fq) ^ (l & 7)) << 3);    // ks=1

    f32x4 acc[4][4];
    #pragma unroll
    for (int m = 0; m < 4; ++m)
        #pragma unroll
        for (int n = 0; n < 4; ++n)
            acc[m][n] = {0.f, 0.f, 0.f, 0.f};

    auto run_seg = [&](const ushort_t* __restrict__ pa,
                       const ushort_t* __restrict__ pb) {
        for (int kt = 0; kt < Kp; kt += 64) {
            // ---- stage: each wave covers 32 rows of As and Bs ----
            #pragma unroll
            for (int i = 0; i < 4; ++i) {
                const int r = w * 32 + i * 8 + rsub;
                int gra = row0 + r; gra = gra < Nr ? gra : Nr - 1;
                const ushort_t* ga = pa + (size_t)gra * Kp + kt + cg;
                __builtin_amdgcn_global_load_lds(
                    (const __attribute__((address_space(1))) void*)ga,
                    (__attribute__((address_space(3))) void*)&As[(w * 32 + i * 8) * 64],
                    16, 0, 0);
                int grb = col0 + r; grb = grb < Mc ? grb : Mc - 1;
                const ushort_t* gb = pb + (size_t)grb * Kp + kt + cg;
                __builtin_amdgcn_global_load_lds(
                    (const __attribute__((address_space(1))) void*)gb,
                    (__attribute__((address_space(3))) void*)&Bs[(w * 32 + i * 8) * 64],
                    16, 0, 0);
            }
            __syncthreads();
            // ---- compute: 2 k-steps of 32, 16 MFMA each ----
            #pragma unroll
            for (int ks = 0; ks < 2; ++ks) {
                const int ca = ks ? ca1 : ca0;
                bf16x8 af[4], bf[4];
                #pragma unroll
                for (int m = 0; m < 4; ++m)
                    af[m] = *reinterpret_cast<const bf16x8*>(
                        &As[(wr * 64 + m * 16 + fr) * 64 + ca]);
                #pragma unroll
                for (int n = 0; n < 4; ++n)
                    bf[n] = *reinterpret_cast<const bf16x8*>(
                        &Bs[(wc * 64 + n * 16 + fr) * 64 + ca]);
                #pragma unroll
                for (int m = 0; m < 4; ++m)
                    #pragma unroll
                    for (int n = 0; n < 4; ++n)
                        acc[m][n] = __builtin_amdgcn_mfma_f32_16x16x32_bf16(
                            af[m], bf[n], acc[m][n], 0, 0, 0);
            }
            __syncthreads();
        }
    };

    run_seg(Ah, Wh);
    run_seg(Ah, Wl);
    run_seg(Al, Wh);

    // ---- epilogue ----
    #pragma unroll
    for (int n = 0; n < 4; ++n) {
        const int col = col0 + wc * 64 + n * 16 + fr;
        if (col >= Mc) continue;
        float bv = 0.f;
        if (col < M1) { if (bias0) bv = bias0[col]; }
        else          { if (bias1) bv = bias1[col - M1]; }
        #pragma unroll
        for (int m = 0; m < 4; ++m) {
            #pragma unroll
            for (int r = 0; r < 4; ++r) {
                const int row = row0 + wr * 64 + m * 16 + fq * 4 + r;
                if (row >= Nr) continue;
                float v = acc[m][n][r] + bv;
                if (act) v = v >= 0.f ? v : v * slope;
                if (col < M1) C0[(size_t)row * ld0 + col] = v;
                else          C1[(size_t)row * ld1 + (col - M1)] = v;
            }
        }
    }
}

// ---------------------------------------------------------------------------
// CSR build: histogram, single-block scan, fill
// ---------------------------------------------------------------------------
__global__ void k_hist(const int* __restrict__ dst, int E, int* __restrict__ cnt)
{
    const int e = blockIdx.x * blockDim.x + threadIdx.x;
    if (e < E) atomicAdd(&cnt[dst[e]], 1);
}

__global__ __launch_bounds__(256) void k_scan(const int* __restrict__ cnt,
                                              int* __restrict__ rs, int n)
{
    __shared__ int sums[256];
    const int tid = threadIdx.x;
    const int T = (n + 255) / 256;
    const int base = tid * T;
    int s = 0;
    for (int i = 0; i < T; ++i) { const int idx = base + i; if (idx < n) s += cnt[idx]; }
    sums[tid] = s;
    __syncthreads();
    for (int o = 1; o < 256; o <<= 1) {
        const int v = (tid >= o) ? sums[tid - o] : 0;
        __syncthreads();
        sums[tid] += v;
        __syncthreads();
    }
    int run = (tid == 0) ? 0 : sums[tid - 1];
    for (int i = 0; i < T; ++i) {
        const int idx = base + i;
        if (idx < n) { rs[idx] = run; run += cnt[idx]; }
    }
    if (tid == 255) rs[n] = sums[255];
}

__global__ void k_fill(const int* __restrict__ src, const int* __restrict__ dst,
                       const float* __restrict__ ew, int E,
                       const int* __restrict__ rs, int* __restrict__ cur,
                       int* __restrict__ csrc, float* __restrict__ cew0,
                       float* __restrict__ cew1)
{
    const int e = blockIdx.x * blockDim.x + threadIdx.x;
    if (e >= E) return;
    const int d = dst[e];
    const int pos = rs[d] + atomicAdd(&cur[d], 1);
    csrc[pos] = src[e];
    cew0[pos] = ew[2 * e];
    cew1[pos] = ew[2 * e + 1];
}

// ---------------------------------------------------------------------------
// za_src / za_dst projections, one wave per node
// ---------------------------------------------------------------------------
__global__ __launch_bounds__(256) void k_dotwa(
    const float* __restrict__ Z, const float* __restrict__ wa, int K, int N,
    float* __restrict__ za_s, float* __restrict__ za_d)
{
    const int lane = threadIdx.x & 63;
    const int node = blockIdx.x * 4 + (threadIdx.x >> 6);
    if (node >= N) return;
    const float* zr = Z + (size_t)node * K;
    float s = 0.f, d = 0.f;
    for (int k = lane; k < K; k += 64) {
        const float zv = zr[k];
        s += zv * wa[k];
        d += zv * wa[K + k];
    }
    #pragma unroll
    for (int o = 32; o; o >>= 1) { s += __shfl_xor(s, o); d += __shfl_xor(d, o); }
    if (lane == 0) { za_s[node] = s; za_d[node] = d; }
}

__global__ __launch_bounds__(256) void k_wasums(const float* __restrict__ wa,
                                                int out, float* __restrict__ sums)
{
    __shared__ float red[256];
    const int tid = threadIdx.x;
    const int half = out >> 1;
    const float* t0 = wa + 2 * out;
    float s0 = 0.f, s1 = 0.f;
    for (int i = tid; i < half; i += 256) { s0 += t0[i]; s1 += t0[half + i]; }
    red[tid] = s0; __syncthreads();
    for (int o = 128; o; o >>= 1) { if (tid < o) red[tid] += red[tid + o]; __syncthreads(); }
    if (tid == 0) sums[0] = red[0];
    __syncthreads();
    red[tid] = s1; __syncthreads();
    for (int o = 128; o; o >>= 1) { if (tid < o) red[tid] += red[tid + o]; __syncthreads(); }
    if (tid == 0) sums[1] = red[0];
}

// ---------------------------------------------------------------------------
// per-dst edge softmax over CSR segment
// ---------------------------------------------------------------------------
__global__ __launch_bounds__(256) void k_attn(
    const int* __restrict__ rs, const int* __restrict__ csrc,
    const float* __restrict__ cew0, const float* __restrict__ cew1,
    const float* __restrict__ za_s, const float* __restrict__ za_d,
    const float* __restrict__ ewsums, float* __restrict__ EV, int N)
{
    const int lane = threadIdx.x & 63;
    const int n = blockIdx.x * 4 + (threadIdx.x >> 6);
    if (n >= N) return;
    const int s0 = rs[n];
    const int cnt = rs[n + 1] - s0;
    if (cnt == 0) return;
    const float zd = za_d[n];
    float w0 = 0.f, w1 = 0.f;
    if (ewsums) { w0 = ewsums[0]; w1 = ewsums[1]; }

    float mx = -INFINITY;
    for (int i = lane; i < cnt; i += 64) {
        float ev = za_s[csrc[s0 + i]] + zd + cew0[s0 + i] * w0 + cew1[s0 + i] * w1;
        ev = ev >= 0.f ? ev : 0.01f * ev;
        EV[s0 + i] = ev;
        mx = fmaxf(mx, ev);
    }
    #pragma unroll
    for (int o = 32; o; o >>= 1) mx = fmaxf(mx, __shfl_xor(mx, o));

    float sum = 0.f;
    for (int i = lane; i < cnt; i += 64) {
        const float ex = expf(EV[s0 + i] - mx);
        EV[s0 + i] = ex;
        sum += ex;
    }
    #pragma unroll
    for (int o = 32; o; o >>= 1) sum += __shfl_xor(sum, o);

    for (int i = lane; i < cnt; i += 64) EV[s0 + i] /= sum;
}

// ---------------------------------------------------------------------------
// aggregate + GAT epilogue
// ---------------------------------------------------------------------------
__global__ __launch_bounds__(256) void k_aggfin(
    const int* __restrict__ rs, const int* __restrict__ csrc,
    const float* __restrict__ EV, const float* __restrict__ Z,
    const float* __restrict__ HS, const float* __restrict__ Hin,
    float* __restrict__ Out, int N, int out, int ldo, int coff)
{
    const int lane = threadIdx.x & 63;
    const int n = blockIdx.x * 4 + (threadIdx.x >> 6);
    if (n >= N) return;
    const int f = blockIdx.y * 64 + lane;
    if (f >= out) return;
    const int s0 = rs[n];
    const int cnt = rs[n + 1] - s0;
    float acc = 0.f;
    for (int i = 0; i < cnt; ++i) {
        const float a = EV[s0 + i];
        const int sn = csrc[s0 + i];
        acc += a * Z[(size_t)sn * out + f];
    }
    const float hv = Hin[(size_t)n * out + f];
    const float hn = (cnt > 0) ? (HS[(size_t)n * out + f] + acc) : hv;
    Out[(size_t)n * ldo + coff + f] = hv + fmaxf(hn, 0.f);
}

// ---------------------------------------------------------------------------
// column-block copy (float4)
// ---------------------------------------------------------------------------
__global__ void k_copy4(const float* __restrict__ src, int s_ld,
                        float* __restrict__ dst, int d_ld, int d_off,
                        int cols, int N)
{
    const int q = cols >> 2;
    const int idx = blockIdx.x * blockDim.x + threadIdx.x;
    if (idx >= N * q) return;
    const int r = idx / q;
    const int c = (idx % q) << 2;
    *reinterpret_cast<float4*>(&dst[(size_t)r * d_ld + d_off + c]) =
        *reinterpret_cast<const float4*>(&src[(size_t)r * s_ld + c]);
}

__global__ void k_reparam(const float* __restrict__ mu, const float* __restrict__ lv,
                          const float* __restrict__ eps, float* __restrict__ z, int total)
{
    const int i = blockIdx.x * blockDim.x + threadIdx.x;
    if (i < total) z[i] = mu[i] + expf(0.5f * lv[i]) * eps[i];
}

// ---------------------------------------------------------------------------
// host side
// ---------------------------------------------------------------------------
static inline void split_mat(hipStream_t st, const float* src, int R, int K, int Kp,
                             ushort_t* oh, ushort_t* ol, int row_off)
{
    const int total = R * (Kp >> 2);
    k_split<<<(total + 255) / 256, 256, 0, st>>>(src, R, K, Kp, oh, ol, row_off);
}

static inline void mgemm(hipStream_t st,
                         const ushort_t* Ah, const ushort_t* Al,
                         const ushort_t* Wh, const ushort_t* Wl,
                         const float* b0, const float* b1,
                         float* C0, int ld0, int M1, float* C1, int ld1,
                         int Nr, int Kp, int Mc, int act, float slope)
{
    dim3 g((Mc + 127) / 128, (Nr + 127) / 128);
    k_mgemm<<<g, 256, 0, st>>>(Ah, Al, Wh, Wl, b0, b1, C0, ld0, M1, C1, ld1,
                               Nr, Kp, Mc, act, slope);
}

struct CsrPtrs {
    const int* rs; const int* csrc; const float* cew0; const float* cew1;
};

static void gat_layer(hipStream_t st, const float* Hin, int dim, int Kp,
                      const ushort_t* Ah, const ushort_t* Al,
                      const float* Ws, const float* Wf, const float* Wa, bool has_ew,
                      ushort_t* Wh, ushort_t* Wl,
                      float* Zb, float* HSb, float* za_s, float* za_d, float* wa_sums,
                      const CsrPtrs& csr, float* EV, float* Out, int ldo, int coff)
{
    split_mat(st, Wf, dim, dim, Kp, Wh, Wl, 0);
    split_mat(st, Ws, dim, dim, Kp, Wh, Wl, dim);
    mgemm(st, Ah, Al, Wh, Wl, nullptr, nullptr,
          Zb, dim, dim, HSb, dim, N_NODES, Kp, 2 * dim, 0, 0.f);
    k_dotwa<<<N_NODES / 4, 256, 0, st>>>(Zb, Wa, dim, N_NODES, za_s, za_d);
    const float* es = nullptr;
    if (has_ew) {
        k_wasums<<<1, 256, 0, st>>>(Wa, dim, wa_sums);
        es = wa_sums;
    }
    k_attn<<<N_NODES / 4, 256, 0, st>>>(csr.rs, csr.csrc, csr.cew0, csr.cew1,
                                        za_s, za_d, es, EV, N_NODES);
    dim3 ga(N_NODES / 4, (dim + 63) / 64);
    k_aggfin<<<ga, 256, 0, st>>>(csr.rs, csr.csrc, EV, Zb, HSb, Hin, Out,
                                 N_NODES, dim, ldo, coff);
}

static inline void copy4(hipStream_t st, const float* src, int s_ld,
                         float* dst, int d_ld, int d_off, int cols)
{
    const int total = N_NODES * (cols >> 2);
    k_copy4<<<(total + 255) / 256, 256, 0, st>>>(src, s_ld, dst, d_ld, d_off, cols, N_NODES);
}

extern "C" void kernel_launch(void* const* d_in, const int* in_sizes, int n_in,
                              void* d_out, int out_size, void* d_ws, size_t ws_size,
                              hipStream_t stream)
{
    const float* feats    = (const float*)d_in[0];
    const float* gt       = (const float*)d_in[1];
    const float* maps_emb = (const float*)d_in[2];
    const float* e_w      = (const float*)d_in[3];
    const float* eps      = (const float*)d_in[4];
    const int*   src      = (const int*)d_in[5];
    const int*   dst      = (const int*)d_in[6];
    const float* emb_W    = (const float*)d_in[7];
    const float* emb_b    = (const float*)d_in[8];
    const float* enc1_Ws  = (const float*)d_in[9];
    const float* enc1_Wf  = (const float*)d_in[10];
    const float* enc1_Wa  = (const float*)d_in[11];
    const float* enc2_Ws  = (const float*)d_in[12];
    const float* enc2_Wf  = (const float*)d_in[13];
    const float* enc2_Wa  = (const float*)d_in[14];
    const float* encmlp_W = (const float*)d_in[15];
    const float* encmlp_b = (const float*)d_in[16];
    const float* mu_W     = (const float*)d_in[17];
    const float* mu_b     = (const float*)d_in[18];
    const float* lv_W     = (const float*)d_in[19];
    const float* lv_b     = (const float*)d_in[20];
    const float* dec1_Ws  = (const float*)d_in[21];
    const float* dec1_Wf  = (const float*)d_in[22];
    const float* dec1_Wa  = (const float*)d_in[23];
    const float* dec2_Ws  = (const float*)d_in[24];
    const float* dec2_Wf  = (const float*)d_in[25];
    const float* dec2_Wa  = (const float*)d_in[26];
    const float* dec0_W   = (const float*)d_in[27];
    const float* dec0_b   = (const float*)d_in[28];
    const float* dec1o_W  = (const float*)d_in[29];
    const float* dec1o_b  = (const float*)d_in[30];

    char* wp = (char*)d_ws;
    size_t off = 0;
    auto alloc_f = [&](size_t nf) -> float* {
        float* p = (float*)(wp + off);
        off = (off + nf * sizeof(float) + 255) & ~(size_t)255;
        return p;
    };
    auto alloc_i = [&](size_t ni) -> int* {
        int* p = (int*)(wp + off);
        off = (off + ni * sizeof(int) + 255) & ~(size_t)255;
        return p;
    };
    auto alloc_u = [&](size_t nu) -> ushort_t* {
        ushort_t* p = (ushort_t*)(wp + off);
        off = (off + nu * sizeof(ushort_t) + 255) & ~(size_t)255;
        return p;
    };

    float* A_CAT   = alloc_f((size_t)N_NODES * 1120);
    float* OUTB    = alloc_f((size_t)N_NODES * 1120);
    float* Zb      = alloc_f((size_t)N_NODES * 1088);
    float* HSb     = alloc_f((size_t)N_NODES * 1088);
    float* h_emb   = alloc_f((size_t)N_NODES * 256);
    float* zlat    = alloc_f((size_t)N_NODES * 32);
    float* za_s    = alloc_f(N_NODES);
    float* za_d    = alloc_f(N_NODES);
    float* EV      = alloc_f(N_EDGES);
    float* cew0    = alloc_f(N_EDGES);
    float* cew1    = alloc_f(N_EDGES);
    float* wa_sums = alloc_f(64);
    int*   cnt     = alloc_i(N_NODES);
    int*   rs      = alloc_i(N_NODES + 1);
    int*   csrc    = alloc_i(N_EDGES);
    ushort_t* Ah   = alloc_u((size_t)N_NODES * 1152);
    ushort_t* Al   = alloc_u((size_t)N_NODES * 1152);
    ushort_t* Wh   = alloc_u((size_t)2176 * 1152);
    ushort_t* Wl   = alloc_u((size_t)2176 * 1152);
    (void)ws_size; (void)in_sizes; (void)n_in; (void)out_size;

    CsrPtrs csr{rs, csrc, cew0, cew1};

    // ---- CSR build ----
    hipMemsetAsync(cnt, 0, N_NODES * sizeof(int), stream);
    k_hist<<<(N_EDGES + 255) / 256, 256, 0, stream>>>(dst, N_EDGES, cnt);
    k_scan<<<1, 256, 0, stream>>>(cnt, rs, N_NODES);
    hipMemsetAsync(cnt, 0, N_NODES * sizeof(int), stream);
    k_fill<<<(N_EDGES + 255) / 256, 256, 0, stream>>>(src, dst, e_w, N_EDGES,
                                                      rs, cnt, csrc, cew0, cew1);

    // ---- embedding: h_emb = feats @ emb_W^T + emb_b ----
    split_mat(stream, feats, N_NODES, 24, 64, Ah, Al, 0);
    split_mat(stream, emb_W, 256, 24, 64, Wh, Wl, 0);
    mgemm(stream, Ah, Al, Wh, Wl, emb_b, nullptr,
          h_emb, 256, 256, h_emb, 256, N_NODES, 64, 256, 0, 0.f);

    // ---- encoder input [maps_emb | h_emb | gt] (536) ----
    copy4(stream, maps_emb, 256, A_CAT, 536, 0, 256);
    copy4(stream, h_emb, 256, A_CAT, 536, 256, 256);
    copy4(stream, gt, 24, A_CAT, 536, 512, 24);

    // ---- encoder GAT layer 1 (2 heads, att_ew) -> OUTB [N,1072] ----
    split_mat(stream, A_CAT, N_NODES, 536, 576, Ah, Al, 0);
    gat_layer(stream, A_CAT, 536, 576, Ah, Al,
              enc1_Ws, enc1_Wf, enc1_Wa, true, Wh, Wl,
              Zb, HSb, za_s, za_d, wa_sums, csr, EV, OUTB, 1072, 0);
    gat_layer(stream, A_CAT, 536, 576, Ah, Al,
              enc1_Ws + 536 * 536, enc1_Wf + 536 * 536, enc1_Wa + 3 * 536, true,
              Wh, Wl, Zb, HSb, za_s, za_d, wa_sums, csr, EV, OUTB, 1072, 536);

    // ---- encoder GAT layer 2 (1 head, att_ew) -> A_CAT [N,1072] ----
    split_mat(stream, OUTB, N_NODES, 1072, 1088, Ah, Al, 0);
    gat_layer(stream, OUTB, 1072, 1088, Ah, Al,
              enc2_Ws, enc2_Wf, enc2_Wa, true, Wh, Wl,
              Zb, HSb, za_s, za_d, wa_sums, csr, EV, A_CAT, 1072, 0);

    // ---- MLP encoder + reparameterize ----
    copy4(stream, A_CAT, 1072, OUTB, 1096, 0, 1072);
    copy4(stream, gt, 24, OUTB, 1096, 1072, 24);
    split_mat(stream, OUTB, N_NODES, 1096, 1152, Ah, Al, 0);
    split_mat(stream, encmlp_W, 548, 1096, 1152, Wh, Wl, 0);
    mgemm(stream, Ah, Al, Wh, Wl, encmlp_b, nullptr,
          Zb, 548, 548, Zb, 548, N_NODES, 1152, 548, 1, 0.01f);
    float* mu = HSb;
    float* lv = HSb + (size_t)N_NODES * 32;
    split_mat(stream, Zb, N_NODES, 548, 576, Ah, Al, 0);
    split_mat(stream, mu_W, 32, 548, 576, Wh, Wl, 0);
    split_mat(stream, lv_W, 32, 548, 576, Wh, Wl, 32);
    mgemm(stream, Ah, Al, Wh, Wl, mu_b, lv_b,
          mu, 32, 32, lv, 32, N_NODES, 576, 64, 0, 0.f);
    k_reparam<<<(N_NODES * 32 + 255) / 256, 256, 0, stream>>>(mu, lv, eps, zlat,
                                                              N_NODES * 32);

    // ---- decoder input [maps_emb | h_emb | z] (544) ----
    copy4(stream, maps_emb, 256, A_CAT, 544, 0, 256);
    copy4(stream, h_emb, 256, A_CAT, 544, 256, 256);
    copy4(stream, zlat, 32, A_CAT, 544, 512, 32);

    // ---- decoder GAT layer 1 (2 heads) -> OUTB [N,1088] ----
    split_mat(stream, A_CAT, N_NODES, 544, 576, Ah, Al, 0);
    gat_layer(stream, A_CAT, 544, 576, Ah, Al,
              dec1_Ws, dec1_Wf, dec1_Wa, false, Wh, Wl,
              Zb, HSb, za_s, za_d, wa_sums, csr, EV, OUTB, 1088, 0);
    gat_layer(stream, A_CAT, 544, 576, Ah, Al,
              dec1_Ws + 544 * 544, dec1_Wf + 544 * 544, dec1_Wa + 2 * 544, false,
              Wh, Wl, Zb, HSb, za_s, za_d, wa_sums, csr, EV, OUTB, 1088, 544);

    // ---- decoder GAT layer 2 (1 head) -> A_CAT [N,1088] ----
    split_mat(stream, OUTB, N_NODES, 1088, 1088, Ah, Al, 0);
    gat_layer(stream, OUTB, 1088, 1088, Ah, Al,
              dec2_Ws, dec2_Wf, dec2_Wa, false, Wh, Wl,
              Zb, HSb, za_s, za_d, wa_sums, csr, EV, A_CAT, 1088, 0);

    // ---- MLP decoder ----
    copy4(stream, A_CAT, 1088, OUTB, 1120, 0, 1088);
    copy4(stream, zlat, 32, OUTB, 1120, 1088, 32);
    split_mat(stream, OUTB, N_NODES, 1120, 1152, Ah, Al, 0);
    split_mat(stream, dec0_W, 544, 1120, 1152, Wh, Wl, 0);
    mgemm(stream, Ah, Al, Wh, Wl, dec0_b, nullptr,
          Zb, 544, 544, Zb, 544, N_NODES, 1152, 544, 1, 0.02f);
    split_mat(stream, Zb, N_NODES, 544, 576, Ah, Al, 0);
    split_mat(stream, dec1o_W, 24, 544, 576, Wh, Wl, 0);
    mgemm(stream, Ah, Al, Wh, Wl, dec1o_b, nullptr,
          (float*)d_out, 24, 24, (float*)d_out, 24, N_NODES, 576, 24, 0, 0.f);
}

// Round 6
// 1859.330 us; speedup vs baseline: 2.2508x; 1.3226x over previous
//
#include <hip/hip_runtime.h>
#include <hip/hip_bf16.h>
#include <hip/hip_fp16.h>

#define N_NODES 10000
#define N_EDGES 160000

typedef __attribute__((ext_vector_type(8))) short bf16x8;
typedef __attribute__((ext_vector_type(4))) float f32x4;
typedef __attribute__((ext_vector_type(4))) unsigned short us4v;
typedef unsigned short ushort_t;

// ---------------------------------------------------------------------------
// fp32 -> (hi,lo) bf16 split with K zero-padding to Kp. 4 elems/thread.
// ---------------------------------------------------------------------------
__device__ __forceinline__ ushort_t f2bf(float x) {
    union { float f; unsigned u; } c; c.f = x;
    unsigned u = c.u;
    u += 0x7fffu + ((u >> 16) & 1u);       // RNE
    return (ushort_t)(u >> 16);
}
__device__ __forceinline__ float bf2f(ushort_t b) {
    union { unsigned u; float f; } c; c.u = ((unsigned)b) << 16;
    return c.f;
}
__device__ __forceinline__ ushort_t f2h(float x) {
    return __half_as_ushort(__float2half(x));
}
__device__ __forceinline__ float h2f(ushort_t h) {
    return __half2float(__ushort_as_half(h));
}

__global__ __launch_bounds__(256) void k_split(
    const float* __restrict__ src, int R, int K, int Kp,
    ushort_t* __restrict__ oh, ushort_t* __restrict__ ol, int row_off)
{
    const int q = Kp >> 2;
    const int idx = blockIdx.x * 256 + threadIdx.x;
    if (idx >= R * q) return;
    const int r = idx / q;
    const int k = (idx - r * q) << 2;
    float4 v = make_float4(0.f, 0.f, 0.f, 0.f);
    if (k < K) v = *reinterpret_cast<const float4*>(&src[(size_t)r * K + k]);
    float vv[4] = {v.x, v.y, v.z, v.w};
    us4v h, l;
    #pragma unroll
    for (int j = 0; j < 4; ++j) {
        const ushort_t hb = f2bf(vv[j]);
        h[j] = hb;
        l[j] = f2bf(vv[j] - bf2f(hb));
    }
    const size_t o = (size_t)(r + row_off) * Kp + k;
    *reinterpret_cast<us4v*>(&oh[o]) = h;
    *reinterpret_cast<us4v*>(&ol[o]) = l;
}

// ---------------------------------------------------------------------------
// bf16 split-MFMA GEMM: C[N,M] = act( (Ah+Al)[N,Kp] @ ((Wh+Wl)[M,Kp])^T + b )
// computed as Ah@Wh + Ah@Wl + Al@Wh. 128x128 tile, BK=64, 4 waves,
// mfma_f32_16x16x32_bf16, global_load_lds staging, XOR chunk swizzle.
// Segment-0 cols: if Z16 != null writes ONLY fp16 (GAT z path, f32 skipped);
// else writes C0 f32. Segment-1 cols always write C1 f32.
// ---------------------------------------------------------------------------
__global__ __launch_bounds__(256) void k_mgemm(
    const ushort_t* __restrict__ Ah, const ushort_t* __restrict__ Al,
    const ushort_t* __restrict__ Wh, const ushort_t* __restrict__ Wl,
    const float* __restrict__ bias0, const float* __restrict__ bias1,
    float* __restrict__ C0, int ld0, int M1,
    float* __restrict__ C1, int ld1,
    ushort_t* __restrict__ Z16, int ld16,
    int Nr, int Kp, int Mc, int act, float slope)
{
    __shared__ ushort_t As[128 * 64];
    __shared__ ushort_t Bs[128 * 64];

    const int tid = threadIdx.x;
    const int w = tid >> 6, l = tid & 63;
    const int wr = w >> 1, wc = w & 1;
    const int row0 = blockIdx.y * 128, col0 = blockIdx.x * 128;

    const int rsub = l >> 3;
    const int cg = (((l & 7) ^ (rsub & 7)) << 3);       // pre-swizzled global chunk
    const int fr = l & 15, fq = l >> 4;
    const int ca0 = (((0 * 4 + fq) ^ (l & 7)) << 3);
    const int ca1 = (((1 * 4 + fq) ^ (l & 7)) << 3);

    f32x4 acc[4][4];
    #pragma unroll
    for (int m = 0; m < 4; ++m)
        #pragma unroll
        for (int n = 0; n < 4; ++n)
            acc[m][n] = {0.f, 0.f, 0.f, 0.f};

    auto run_seg = [&](const ushort_t* __restrict__ pa,
                       const ushort_t* __restrict__ pb) {
        for (int kt = 0; kt < Kp; kt += 64) {
            #pragma unroll
            for (int i = 0; i < 4; ++i) {
                const int r = w * 32 + i * 8 + rsub;
                int gra = row0 + r; gra = gra < Nr ? gra : Nr - 1;
                const ushort_t* ga = pa + (size_t)gra * Kp + kt + cg;
                __builtin_amdgcn_global_load_lds(
                    (const __attribute__((address_space(1))) void*)ga,
                    (__attribute__((address_space(3))) void*)&As[(w * 32 + i * 8) * 64],
                    16, 0, 0);
                int grb = col0 + r; grb = grb < Mc ? grb : Mc - 1;
                const ushort_t* gb = pb + (size_t)grb * Kp + kt + cg;
                __builtin_amdgcn_global_load_lds(
                    (const __attribute__((address_space(1))) void*)gb,
                    (__attribute__((address_space(3))) void*)&Bs[(w * 32 + i * 8) * 64],
                    16, 0, 0);
            }
            __syncthreads();
            #pragma unroll
            for (int ks = 0; ks < 2; ++ks) {
                const int ca = ks ? ca1 : ca0;
                bf16x8 af[4], bf[4];
                #pragma unroll
                for (int m = 0; m < 4; ++m)
                    af[m] = *reinterpret_cast<const bf16x8*>(
                        &As[(wr * 64 + m * 16 + fr) * 64 + ca]);
                #pragma unroll
                for (int n = 0; n < 4; ++n)
                    bf[n] = *reinterpret_cast<const bf16x8*>(
                        &Bs[(wc * 64 + n * 16 + fr) * 64 + ca]);
                #pragma unroll
                for (int m = 0; m < 4; ++m)
                    #pragma unroll
                    for (int n = 0; n < 4; ++n)
                        acc[m][n] = __builtin_amdgcn_mfma_f32_16x16x32_bf16(
                            af[m], bf[n], acc[m][n], 0, 0, 0);
            }
            __syncthreads();
        }
    };

    run_seg(Ah, Wh);
    run_seg(Ah, Wl);
    run_seg(Al, Wh);

    #pragma unroll
    for (int n = 0; n < 4; ++n) {
        const int col = col0 + wc * 64 + n * 16 + fr;
        if (col >= Mc) continue;
        float bv = 0.f;
        if (col < M1) { if (bias0) bv = bias0[col]; }
        else          { if (bias1) bv = bias1[col - M1]; }
        #pragma unroll
        for (int m = 0; m < 4; ++m) {
            #pragma unroll
            for (int r = 0; r < 4; ++r) {
                const int row = row0 + wr * 64 + m * 16 + fq * 4 + r;
                if (row >= Nr) continue;
                float v = acc[m][n][r] + bv;
                if (act) v = v >= 0.f ? v : v * slope;
                if (col < M1) {
                    if (Z16) Z16[(size_t)row * ld16 + col] = f2h(v);
                    else     C0[(size_t)row * ld0 + col] = v;
                } else {
                    C1[(size_t)row * ld1 + (col - M1)] = v;
                }
            }
        }
    }
}

// ---------------------------------------------------------------------------
// CSR build: histogram, single-block scan, fill
// ---------------------------------------------------------------------------
__global__ void k_hist(const int* __restrict__ dst, int E, int* __restrict__ cnt)
{
    const int e = blockIdx.x * blockDim.x + threadIdx.x;
    if (e < E) atomicAdd(&cnt[dst[e]], 1);
}

__global__ __launch_bounds__(256) void k_scan(const int* __restrict__ cnt,
                                              int* __restrict__ rs, int n)
{
    __shared__ int sums[256];
    const int tid = threadIdx.x;
    const int T = (n + 255) / 256;
    const int base = tid * T;
    int s = 0;
    for (int i = 0; i < T; ++i) { const int idx = base + i; if (idx < n) s += cnt[idx]; }
    sums[tid] = s;
    __syncthreads();
    for (int o = 1; o < 256; o <<= 1) {
        const int v = (tid >= o) ? sums[tid - o] : 0;
        __syncthreads();
        sums[tid] += v;
        __syncthreads();
    }
    int run = (tid == 0) ? 0 : sums[tid - 1];
    for (int i = 0; i < T; ++i) {
        const int idx = base + i;
        if (idx < n) { rs[idx] = run; run += cnt[idx]; }
    }
    if (tid == 255) rs[n] = sums[255];
}

__global__ void k_fill(const int* __restrict__ src, const int* __restrict__ dst,
                       const float* __restrict__ ew, int E,
                       const int* __restrict__ rs, int* __restrict__ cur,
                       int* __restrict__ csrc, float* __restrict__ cew0,
                       float* __restrict__ cew1)
{
    const int e = blockIdx.x * blockDim.x + threadIdx.x;
    if (e >= E) return;
    const int d = dst[e];
    const int pos = rs[d] + atomicAdd(&cur[d], 1);
    csrc[pos] = src[e];
    cew0[pos] = ew[2 * e];
    cew1[pos] = ew[2 * e + 1];
}

// ---------------------------------------------------------------------------
// za_src / za_dst projections from fp16 z, one wave per node
// ---------------------------------------------------------------------------
__global__ __launch_bounds__(256) void k_dotwa(
    const ushort_t* __restrict__ Z16, const float* __restrict__ wa, int K, int N,
    float* __restrict__ za_s, float* __restrict__ za_d)
{
    const int lane = threadIdx.x & 63;
    const int node = blockIdx.x * 4 + (threadIdx.x >> 6);
    if (node >= N) return;
    const ushort_t* zr = Z16 + (size_t)node * K;
    float s = 0.f, d = 0.f;
    for (int k = lane; k < K; k += 64) {
        const float zv = h2f(zr[k]);
        s += zv * wa[k];
        d += zv * wa[K + k];
    }
    #pragma unroll
    for (int o = 32; o; o >>= 1) { s += __shfl_xor(s, o); d += __shfl_xor(d, o); }
    if (lane == 0) { za_s[node] = s; za_d[node] = d; }
}

__global__ __launch_bounds__(256) void k_wasums(const float* __restrict__ wa,
                                                int out, float* __restrict__ sums)
{
    __shared__ float red[256];
    const int tid = threadIdx.x;
    const int half = out >> 1;
    const float* t0 = wa + 2 * out;
    float s0 = 0.f, s1 = 0.f;
    for (int i = tid; i < half; i += 256) { s0 += t0[i]; s1 += t0[half + i]; }
    red[tid] = s0; __syncthreads();
    for (int o = 128; o; o >>= 1) { if (tid < o) red[tid] += red[tid + o]; __syncthreads(); }
    if (tid == 0) sums[0] = red[0];
    __syncthreads();
    red[tid] = s1; __syncthreads();
    for (int o = 128; o; o >>= 1) { if (tid < o) red[tid] += red[tid + o]; __syncthreads(); }
    if (tid == 0) sums[1] = red[0];
}

// ---------------------------------------------------------------------------
// per-dst edge softmax over CSR segment
// ---------------------------------------------------------------------------
__global__ __launch_bounds__(256) void k_attn(
    const int* __restrict__ rs, const int* __restrict__ csrc,
    const float* __restrict__ cew0, const float* __restrict__ cew1,
    const float* __restrict__ za_s, const float* __restrict__ za_d,
    const float* __restrict__ ewsums, float* __restrict__ EV, int N)
{
    const int lane = threadIdx.x & 63;
    const int n = blockIdx.x * 4 + (threadIdx.x >> 6);
    if (n >= N) return;
    const int s0 = rs[n];
    const int cnt = rs[n + 1] - s0;
    if (cnt == 0) return;
    const float zd = za_d[n];
    float w0 = 0.f, w1 = 0.f;
    if (ewsums) { w0 = ewsums[0]; w1 = ewsums[1]; }

    float mx = -INFINITY;
    for (int i = lane; i < cnt; i += 64) {
        float ev = za_s[csrc[s0 + i]] + zd + cew0[s0 + i] * w0 + cew1[s0 + i] * w1;
        ev = ev >= 0.f ? ev : 0.01f * ev;
        EV[s0 + i] = ev;
        mx = fmaxf(mx, ev);
    }
    #pragma unroll
    for (int o = 32; o; o >>= 1) mx = fmaxf(mx, __shfl_xor(mx, o));

    float sum = 0.f;
    for (int i = lane; i < cnt; i += 64) {
        const float ex = expf(EV[s0 + i] - mx);
        EV[s0 + i] = ex;
        sum += ex;
    }
    #pragma unroll
    for (int o = 32; o; o >>= 1) sum += __shfl_xor(sum, o);

    for (int i = lane; i < cnt; i += 64) EV[s0 + i] /= sum;
}

// ---------------------------------------------------------------------------
// aggregate + GAT epilogue. fp16 Z gather, 2 features/lane, 2-edge unroll.
// one wave per (node, 128-feature chunk); non-atomic owned writes.
// ---------------------------------------------------------------------------
__global__ __launch_bounds__(256) void k_aggfin(
    const int* __restrict__ rs, const int* __restrict__ csrc,
    const float* __restrict__ EV, const ushort_t* __restrict__ Z16,
    const float* __restrict__ HS, const float* __restrict__ Hin,
    float* __restrict__ Out, int N, int out, int ldo, int coff)
{
    const int lane = threadIdx.x & 63;
    const int n = blockIdx.x * 4 + (threadIdx.x >> 6);
    if (n >= N) return;
    const int f = blockIdx.y * 128 + lane * 2;
    if (f >= out) return;
    const int s0 = rs[n];
    const int cnt = rs[n + 1] - s0;

    float ax = 0.f, ay = 0.f, bx = 0.f, by = 0.f;
    int i = 0;
    for (; i + 2 <= cnt; i += 2) {
        const int sn0 = csrc[s0 + i];
        const int sn1 = csrc[s0 + i + 1];
        const float w0 = EV[s0 + i];
        const float w1 = EV[s0 + i + 1];
        union { unsigned u; __half2 h; } c0, c1;
        c0.u = *reinterpret_cast<const unsigned*>(&Z16[(size_t)sn0 * out + f]);
        c1.u = *reinterpret_cast<const unsigned*>(&Z16[(size_t)sn1 * out + f]);
        const float2 z0 = __half22float2(c0.h);
        const float2 z1 = __half22float2(c1.h);
        ax += w0 * z0.x; ay += w0 * z0.y;
        bx += w1 * z1.x; by += w1 * z1.y;
    }
    if (i < cnt) {
        const int sn0 = csrc[s0 + i];
        const float w0 = EV[s0 + i];
        union { unsigned u; __half2 h; } c0;
        c0.u = *reinterpret_cast<const unsigned*>(&Z16[(size_t)sn0 * out + f]);
        const float2 z0 = __half22float2(c0.h);
        ax += w0 * z0.x; ay += w0 * z0.y;
    }
    const float accx = ax + bx, accy = ay + by;

    const float2 hv = *reinterpret_cast<const float2*>(&Hin[(size_t)n * out + f]);
    const float2 hs = *reinterpret_cast<const float2*>(&HS[(size_t)n * out + f]);
    const float hnx = (cnt > 0) ? (hs.x + accx) : hv.x;
    const float hny = (cnt > 0) ? (hs.y + accy) : hv.y;
    float2 o;
    o.x = hv.x + fmaxf(hnx, 0.f);
    o.y = hv.y + fmaxf(hny, 0.f);
    *reinterpret_cast<float2*>(&Out[(size_t)n * ldo + coff + f]) = o;
}

// ---------------------------------------------------------------------------
// column-block copy (float4)
// ---------------------------------------------------------------------------
__global__ void k_copy4(const float* __restrict__ src, int s_ld,
                        float* __restrict__ dst, int d_ld, int d_off,
                        int cols, int N)
{
    const int q = cols >> 2;
    const int idx = blockIdx.x * blockDim.x + threadIdx.x;
    if (idx >= N * q) return;
    const int r = idx / q;
    const int c = (idx % q) << 2;
    *reinterpret_cast<float4*>(&dst[(size_t)r * d_ld + d_off + c]) =
        *reinterpret_cast<const float4*>(&src[(size_t)r * s_ld + c]);
}

__global__ void k_reparam(const float* __restrict__ mu, const float* __restrict__ lv,
                          const float* __restrict__ eps, float* __restrict__ z, int total)
{
    const int i = blockIdx.x * blockDim.x + threadIdx.x;
    if (i < total) z[i] = mu[i] + expf(0.5f * lv[i]) * eps[i];
}

// ---------------------------------------------------------------------------
// host side
// ---------------------------------------------------------------------------
static inline void split_mat(hipStream_t st, const float* src, int R, int K, int Kp,
                             ushort_t* oh, ushort_t* ol, int row_off)
{
    const int total = R * (Kp >> 2);
    k_split<<<(total + 255) / 256, 256, 0, st>>>(src, R, K, Kp, oh, ol, row_off);
}

static inline void mgemm(hipStream_t st,
                         const ushort_t* Ah, const ushort_t* Al,
                         const ushort_t* Wh, const ushort_t* Wl,
                         const float* b0, const float* b1,
                         float* C0, int ld0, int M1, float* C1, int ld1,
                         ushort_t* Z16, int ld16,
                         int Nr, int Kp, int Mc, int act, float slope)
{
    dim3 g((Mc + 127) / 128, (Nr + 127) / 128);
    k_mgemm<<<g, 256, 0, st>>>(Ah, Al, Wh, Wl, b0, b1, C0, ld0, M1, C1, ld1,
                               Z16, ld16, Nr, Kp, Mc, act, slope);
}

struct CsrPtrs {
    const int* rs; const int* csrc; const float* cew0; const float* cew1;
};

static void gat_layer(hipStream_t st, const float* Hin, int dim, int Kp,
                      const ushort_t* Ah, const ushort_t* Al,
                      const float* Ws, const float* Wf, const float* Wa, bool has_ew,
                      ushort_t* Wh, ushort_t* Wl,
                      ushort_t* Z16, float* HSb,
                      float* za_s, float* za_d, float* wa_sums,
                      const CsrPtrs& csr, float* EV, float* Out, int ldo, int coff)
{
    split_mat(st, Wf, dim, dim, Kp, Wh, Wl, 0);
    split_mat(st, Ws, dim, dim, Kp, Wh, Wl, dim);
    // z -> Z16 (fp16 only), h_s -> HSb (f32)
    mgemm(st, Ah, Al, Wh, Wl, nullptr, nullptr,
          nullptr, dim, dim, HSb, dim, Z16, dim, N_NODES, Kp, 2 * dim, 0, 0.f);
    k_dotwa<<<N_NODES / 4, 256, 0, st>>>(Z16, Wa, dim, N_NODES, za_s, za_d);
    const float* es = nullptr;
    if (has_ew) {
        k_wasums<<<1, 256, 0, st>>>(Wa, dim, wa_sums);
        es = wa_sums;
    }
    k_attn<<<N_NODES / 4, 256, 0, st>>>(csr.rs, csr.csrc, csr.cew0, csr.cew1,
                                        za_s, za_d, es, EV, N_NODES);
    dim3 ga(N_NODES / 4, (dim + 127) / 128);
    k_aggfin<<<ga, 256, 0, st>>>(csr.rs, csr.csrc, EV, Z16, HSb, Hin, Out,
                                 N_NODES, dim, ldo, coff);
}

static inline void copy4(hipStream_t st, const float* src, int s_ld,
                         float* dst, int d_ld, int d_off, int cols)
{
    const int total = N_NODES * (cols >> 2);
    k_copy4<<<(total + 255) / 256, 256, 0, st>>>(src, s_ld, dst, d_ld, d_off, cols, N_NODES);
}

extern "C" void kernel_launch(void* const* d_in, const int* in_sizes, int n_in,
                              void* d_out, int out_size, void* d_ws, size_t ws_size,
                              hipStream_t stream)
{
    const float* feats    = (const float*)d_in[0];
    const float* gt       = (const float*)d_in[1];
    const float* maps_emb = (const float*)d_in[2];
    const float* e_w      = (const float*)d_in[3];
    const float* eps      = (const float*)d_in[4];
    const int*   src      = (const int*)d_in[5];
    const int*   dst      = (const int*)d_in[6];
    const float* emb_W    = (const float*)d_in[7];
    const float* emb_b    = (const float*)d_in[8];
    const float* enc1_Ws  = (const float*)d_in[9];
    const float* enc1_Wf  = (const float*)d_in[10];
    const float* enc1_Wa  = (const float*)d_in[11];
    const float* enc2_Ws  = (const float*)d_in[12];
    const float* enc2_Wf  = (const float*)d_in[13];
    const float* enc2_Wa  = (const float*)d_in[14];
    const float* encmlp_W = (const float*)d_in[15];
    const float* encmlp_b = (const float*)d_in[16];
    const float* mu_W     = (const float*)d_in[17];
    const float* mu_b     = (const float*)d_in[18];
    const float* lv_W     = (const float*)d_in[19];
    const float* lv_b     = (const float*)d_in[20];
    const float* dec1_Ws  = (const float*)d_in[21];
    const float* dec1_Wf  = (const float*)d_in[22];
    const float* dec1_Wa  = (const float*)d_in[23];
    const float* dec2_Ws  = (const float*)d_in[24];
    const float* dec2_Wf  = (const float*)d_in[25];
    const float* dec2_Wa  = (const float*)d_in[26];
    const float* dec0_W   = (const float*)d_in[27];
    const float* dec0_b   = (const float*)d_in[28];
    const float* dec1o_W  = (const float*)d_in[29];
    const float* dec1o_b  = (const float*)d_in[30];

    char* wp = (char*)d_ws;
    size_t off = 0;
    auto alloc_f = [&](size_t nf) -> float* {
        float* p = (float*)(wp + off);
        off = (off + nf * sizeof(float) + 255) & ~(size_t)255;
        return p;
    };
    auto alloc_i = [&](size_t ni) -> int* {
        int* p = (int*)(wp + off);
        off = (off + ni * sizeof(int) + 255) & ~(size_t)255;
        return p;
    };
    auto alloc_u = [&](size_t nu) -> ushort_t* {
        ushort_t* p = (ushort_t*)(wp + off);
        off = (off + nu * sizeof(ushort_t) + 255) & ~(size_t)255;
        return p;
    };

    // total ≈ 245.3 MB (R2's known-good layout was 247.0 MB; R5's 268.8 crashed)
    float* A_CAT   = alloc_f((size_t)N_NODES * 1088);
    float* OUTB    = alloc_f((size_t)N_NODES * 1120);
    float* Zb      = alloc_f((size_t)N_NODES * 548);   // MLP intermediates only
    float* HSb     = alloc_f((size_t)N_NODES * 1088);
    float* h_emb   = alloc_f((size_t)N_NODES * 256);
    float* zlat    = alloc_f((size_t)N_NODES * 32);
    float* za_s    = alloc_f(N_NODES);
    float* za_d    = alloc_f(N_NODES);
    float* EV      = alloc_f(N_EDGES);
    float* cew0    = alloc_f(N_EDGES);
    float* cew1    = alloc_f(N_EDGES);
    float* wa_sums = alloc_f(64);
    int*   cnt     = alloc_i(N_NODES);
    int*   rs      = alloc_i(N_NODES + 1);
    int*   csrc    = alloc_i(N_EDGES);
    ushort_t* Ah   = alloc_u((size_t)N_NODES * 1152);
    ushort_t* Al   = alloc_u((size_t)N_NODES * 1152);
    ushort_t* Wh   = alloc_u((size_t)2176 * 1088);
    ushort_t* Wl   = alloc_u((size_t)2176 * 1088);
    ushort_t* Z16  = alloc_u((size_t)N_NODES * 1088);
    (void)ws_size; (void)in_sizes; (void)n_in; (void)out_size;

    CsrPtrs csr{rs, csrc, cew0, cew1};

    // ---- CSR build ----
    hipMemsetAsync(cnt, 0, N_NODES * sizeof(int), stream);
    k_hist<<<(N_EDGES + 255) / 256, 256, 0, stream>>>(dst, N_EDGES, cnt);
    k_scan<<<1, 256, 0, stream>>>(cnt, rs, N_NODES);
    hipMemsetAsync(cnt, 0, N_NODES * sizeof(int), stream);
    k_fill<<<(N_EDGES + 255) / 256, 256, 0, stream>>>(src, dst, e_w, N_EDGES,
                                                      rs, cnt, csrc, cew0, cew1);

    // ---- embedding: h_emb = feats @ emb_W^T + emb_b ----
    split_mat(stream, feats, N_NODES, 24, 64, Ah, Al, 0);
    split_mat(stream, emb_W, 256, 24, 64, Wh, Wl, 0);
    mgemm(stream, Ah, Al, Wh, Wl, emb_b, nullptr,
          h_emb, 256, 256, h_emb, 256, nullptr, 0, N_NODES, 64, 256, 0, 0.f);

    // ---- encoder input [maps_emb | h_emb | gt] (536) ----
    copy4(stream, maps_emb, 256, A_CAT, 536, 0, 256);
    copy4(stream, h_emb, 256, A_CAT, 536, 256, 256);
    copy4(stream, gt, 24, A_CAT, 536, 512, 24);

    // ---- encoder GAT layer 1 (2 heads, att_ew) -> OUTB [N,1072] ----
    split_mat(stream, A_CAT, N_NODES, 536, 576, Ah, Al, 0);
    gat_layer(stream, A_CAT, 536, 576, Ah, Al,
              enc1_Ws, enc1_Wf, enc1_Wa, true, Wh, Wl,
              Z16, HSb, za_s, za_d, wa_sums, csr, EV, OUTB, 1072, 0);
    gat_layer(stream, A_CAT, 536, 576, Ah, Al,
              enc1_Ws + 536 * 536, enc1_Wf + 536 * 536, enc1_Wa + 3 * 536, true,
              Wh, Wl, Z16, HSb, za_s, za_d, wa_sums, csr, EV, OUTB, 1072, 536);

    // ---- encoder GAT layer 2 (1 head, att_ew) -> A_CAT [N,1072] ----
    split_mat(stream, OUTB, N_NODES, 1072, 1088, Ah, Al, 0);
    gat_layer(stream, OUTB, 1072, 1088, Ah, Al,
              enc2_Ws, enc2_Wf, enc2_Wa, true, Wh, Wl,
              Z16, HSb, za_s, za_d, wa_sums, csr, EV, A_CAT, 1072, 0);

    // ---- MLP encoder + reparameterize ----
    copy4(stream, A_CAT, 1072, OUTB, 1096, 0, 1072);
    copy4(stream, gt, 24, OUTB, 1096, 1072, 24);
    split_mat(stream, OUTB, N_NODES, 1096, 1152, Ah, Al, 0);
    split_mat(stream, encmlp_W, 548, 1096, 1152, Wh, Wl, 0);
    mgemm(stream, Ah, Al, Wh, Wl, encmlp_b, nullptr,
          Zb, 548, 548, Zb, 548, nullptr, 0, N_NODES, 1152, 548, 1, 0.01f);
    float* mu = HSb;
    float* lv = HSb + (size_t)N_NODES * 32;
    split_mat(stream, Zb, N_NODES, 548, 576, Ah, Al, 0);
    split_mat(stream, mu_W, 32, 548, 576, Wh, Wl, 0);
    split_mat(stream, lv_W, 32, 548, 576, Wh, Wl, 32);
    mgemm(stream, Ah, Al, Wh, Wl, mu_b, lv_b,
          mu, 32, 32, lv, 32, nullptr, 0, N_NODES, 576, 64, 0, 0.f);
    k_reparam<<<(N_NODES * 32 + 255) / 256, 256, 0, stream>>>(mu, lv, eps, zlat,
                                                              N_NODES * 32);

    // ---- decoder input [maps_emb | h_emb | z] (544) ----
    copy4(stream, maps_emb, 256, A_CAT, 544, 0, 256);
    copy4(stream, h_emb, 256, A_CAT, 544, 256, 256);
    copy4(stream, zlat, 32, A_CAT, 544, 512, 32);

    // ---- decoder GAT layer 1 (2 heads) -> OUTB [N,1088] ----
    split_mat(stream, A_CAT, N_NODES, 544, 576, Ah, Al, 0);
    gat_layer(stream, A_CAT, 544, 576, Ah, Al,
              dec1_Ws, dec1_Wf, dec1_Wa, false, Wh, Wl,
              Z16, HSb, za_s, za_d, wa_sums, csr, EV, OUTB, 1088, 0);
    gat_layer(stream, A_CAT, 544, 576, Ah, Al,
              dec1_Ws + 544 * 544, dec1_Wf + 544 * 544, dec1_Wa + 2 * 544, false,
              Wh, Wl, Z16, HSb, za_s, za_d, wa_sums, csr, EV, OUTB, 1088, 544);

    // ---- decoder GAT layer 2 (1 head) -> A_CAT [N,1088] ----
    split_mat(stream, OUTB, N_NODES, 1088, 1088, Ah, Al, 0);
    gat_layer(stream, OUTB, 1088, 1088, Ah, Al,
              dec2_Ws, dec2_Wf, dec2_Wa, false, Wh, Wl,
              Z16, HSb, za_s, za_d, wa_sums, csr, EV, A_CAT, 1088, 0);

    // ---- MLP decoder ----
    copy4(stream, A_CAT, 1088, OUTB, 1120, 0, 1088);
    copy4(stream, zlat, 32, OUTB, 1120, 1088, 32);
    split_mat(stream, OUTB, N_NODES, 1120, 1152, Ah, Al, 0);
    split_mat(stream, dec0_W, 544, 1120, 1152, Wh, Wl, 0);
    mgemm(stream, Ah, Al, Wh, Wl, dec0_b, nullptr,
          Zb, 544, 544, Zb, 544, nullptr, 0, N_NODES, 1152, 544, 1, 0.02f);
    split_mat(stream, Zb, N_NODES, 544, 576, Ah, Al, 0);
    split_mat(stream, dec1o_W, 24, 544, 576, Wh, Wl, 0);
    mgemm(stream, Ah, Al, Wh, Wl, dec1o_b, nullptr,
          (float*)d_out, 24, 24, (float*)d_out, 24, nullptr, 0, N_NODES, 576, 24, 0, 0.f);
}

// Round 13
// 1534.051 us; speedup vs baseline: 2.7280x; 1.2120x over previous
//
#include <hip/hip_runtime.h>
#include <hip/hip_bf16.h>
#include <hip/hip_fp16.h>

#define N_NODES 10000
#define N_EDGES 160000

typedef __attribute__((ext_vector_type(8))) short bf16x8;
typedef __attribute__((ext_vector_type(4))) float f32x4;
typedef __attribute__((ext_vector_type(4))) unsigned short us4v;
typedef unsigned short ushort_t;

// ---------------------------------------------------------------------------
// fp32 -> (hi,lo) bf16 split with K zero-padding to Kp. 4 elems/thread.
// ---------------------------------------------------------------------------
__device__ __forceinline__ ushort_t f2bf(float x) {
    union { float f; unsigned u; } c; c.f = x;
    unsigned u = c.u;
    u += 0x7fffu + ((u >> 16) & 1u);       // RNE
    return (ushort_t)(u >> 16);
}
__device__ __forceinline__ float bf2f(ushort_t b) {
    union { unsigned u; float f; } c; c.u = ((unsigned)b) << 16;
    return c.f;
}
__device__ __forceinline__ ushort_t f2h(float x) {
    return __half_as_ushort(__float2half(x));
}
__device__ __forceinline__ float h2f(ushort_t h) {
    return __half2float(__ushort_as_half(h));
}

__global__ __launch_bounds__(256) void k_split(
    const float* __restrict__ src, int R, int K, int Kp,
    ushort_t* __restrict__ oh, ushort_t* __restrict__ ol, int row_off)
{
    const int q = Kp >> 2;
    const int idx = blockIdx.x * 256 + threadIdx.x;
    if (idx >= R * q) return;
    const int r = idx / q;
    const int k = (idx - r * q) << 2;
    float4 v = make_float4(0.f, 0.f, 0.f, 0.f);
    if (k < K) v = *reinterpret_cast<const float4*>(&src[(size_t)r * K + k]);
    float vv[4] = {v.x, v.y, v.z, v.w};
    us4v h, l;
    #pragma unroll
    for (int j = 0; j < 4; ++j) {
        const ushort_t hb = f2bf(vv[j]);
        h[j] = hb;
        l[j] = f2bf(vv[j] - bf2f(hb));
    }
    const size_t o = (size_t)(r + row_off) * Kp + k;
    *reinterpret_cast<us4v*>(&oh[o]) = h;
    *reinterpret_cast<us4v*>(&ol[o]) = l;
}

// ---------------------------------------------------------------------------
// bf16 split-MFMA GEMM, FUSED hi/lo K-loop:
//   C = Ah@Wh + Ah@Wl + Al@Wh  (one pass over K; 4 tiles staged per k-step,
//   48 MFMA per 16 ds_read_b128, one barrier pair per k-step)
// mode 0: two-segment f32 epilogue (col<M1 -> C0+bias0, else C1+bias1), act.
// mode 1: GAT interleaved epilogue over dim-sized segments (M1=dim):
//   seg even -> Z16 fp16 at col (seg>>1)*M1+rem, stride ld16
//   seg odd  -> C1  f32  at col (seg>>1)*M1+rem, stride ld1  (no bias/act)
// ---------------------------------------------------------------------------
__global__ __launch_bounds__(256) void k_mgemm(
    const ushort_t* __restrict__ Ah, const ushort_t* __restrict__ Al,
    const ushort_t* __restrict__ Wh, const ushort_t* __restrict__ Wl,
    const float* __restrict__ bias0, const float* __restrict__ bias1,
    float* __restrict__ C0, int ld0, int M1,
    float* __restrict__ C1, int ld1,
    ushort_t* __restrict__ Z16, int ld16,
    int Nr, int Kp, int Mc, int act, float slope, int mode)
{
    __shared__ ushort_t As0[128 * 64];
    __shared__ ushort_t As1[128 * 64];
    __shared__ ushort_t Bs0[128 * 64];
    __shared__ ushort_t Bs1[128 * 64];

    const int tid = threadIdx.x;
    const int w = tid >> 6, l = tid & 63;
    const int wr = w >> 1, wc = w & 1;
    const int row0 = blockIdx.y * 128, col0 = blockIdx.x * 128;

    const int rsub = l >> 3;
    const int cg = (((l & 7) ^ (rsub & 7)) << 3);       // pre-swizzled global chunk
    const int fr = l & 15, fq = l >> 4;
    const int ca0 = (((0 * 4 + fq) ^ (l & 7)) << 3);
    const int ca1 = (((1 * 4 + fq) ^ (l & 7)) << 3);

    f32x4 acc[4][4];
    #pragma unroll
    for (int m = 0; m < 4; ++m)
        #pragma unroll
        for (int n = 0; n < 4; ++n)
            acc[m][n] = {0.f, 0.f, 0.f, 0.f};

    for (int kt = 0; kt < Kp; kt += 64) {
        #pragma unroll
        for (int i = 0; i < 4; ++i) {
            const int r = w * 32 + i * 8 + rsub;
            const int lofs = (w * 32 + i * 8) * 64;
            int gra = row0 + r; gra = gra < Nr ? gra : Nr - 1;
            const size_t aoff = (size_t)gra * Kp + kt + cg;
            __builtin_amdgcn_global_load_lds(
                (const __attribute__((address_space(1))) void*)(Ah + aoff),
                (__attribute__((address_space(3))) void*)&As0[lofs], 16, 0, 0);
            __builtin_amdgcn_global_load_lds(
                (const __attribute__((address_space(1))) void*)(Al + aoff),
                (__attribute__((address_space(3))) void*)&As1[lofs], 16, 0, 0);
            int grb = col0 + r; grb = grb < Mc ? grb : Mc - 1;
            const size_t boff = (size_t)grb * Kp + kt + cg;
            __builtin_amdgcn_global_load_lds(
                (const __attribute__((address_space(1))) void*)(Wh + boff),
                (__attribute__((address_space(3))) void*)&Bs0[lofs], 16, 0, 0);
            __builtin_amdgcn_global_load_lds(
                (const __attribute__((address_space(1))) void*)(Wl + boff),
                (__attribute__((address_space(3))) void*)&Bs1[lofs], 16, 0, 0);
        }
        __syncthreads();
        #pragma unroll
        for (int ks = 0; ks < 2; ++ks) {
            const int ca = ks ? ca1 : ca0;
            bf16x8 ah[4], al4[4], bh[4], bl4[4];
            #pragma unroll
            for (int m = 0; m < 4; ++m) {
                const int ro = (wr * 64 + m * 16 + fr) * 64 + ca;
                ah[m]  = *reinterpret_cast<const bf16x8*>(&As0[ro]);
                al4[m] = *reinterpret_cast<const bf16x8*>(&As1[ro]);
            }
            #pragma unroll
            for (int n = 0; n < 4; ++n) {
                const int ro = (wc * 64 + n * 16 + fr) * 64 + ca;
                bh[n]  = *reinterpret_cast<const bf16x8*>(&Bs0[ro]);
                bl4[n] = *reinterpret_cast<const bf16x8*>(&Bs1[ro]);
            }
            #pragma unroll
            for (int m = 0; m < 4; ++m)
                #pragma unroll
                for (int n = 0; n < 4; ++n) {
                    acc[m][n] = __builtin_amdgcn_mfma_f32_16x16x32_bf16(
                        ah[m], bh[n], acc[m][n], 0, 0, 0);
                    acc[m][n] = __builtin_amdgcn_mfma_f32_16x16x32_bf16(
                        ah[m], bl4[n], acc[m][n], 0, 0, 0);
                    acc[m][n] = __builtin_amdgcn_mfma_f32_16x16x32_bf16(
                        al4[m], bh[n], acc[m][n], 0, 0, 0);
                }
        }
        __syncthreads();
    }

    #pragma unroll
    for (int n = 0; n < 4; ++n) {
        const int col = col0 + wc * 64 + n * 16 + fr;
        if (col >= Mc) continue;
        if (mode == 0) {
            float bv = 0.f;
            if (col < M1) { if (bias0) bv = bias0[col]; }
            else          { if (bias1) bv = bias1[col - M1]; }
            #pragma unroll
            for (int m = 0; m < 4; ++m) {
                #pragma unroll
                for (int r = 0; r < 4; ++r) {
                    const int row = row0 + wr * 64 + m * 16 + fq * 4 + r;
                    if (row >= Nr) continue;
                    float v = acc[m][n][r] + bv;
                    if (act) v = v >= 0.f ? v : v * slope;
                    if (col < M1) C0[(size_t)row * ld0 + col] = v;
                    else          C1[(size_t)row * ld1 + (col - M1)] = v;
                }
            }
        } else {
            const int seg = col / M1;
            const int rem = col - seg * M1;
            const int oc = (seg >> 1) * M1 + rem;
            const bool to_z = (seg & 1) == 0;
            #pragma unroll
            for (int m = 0; m < 4; ++m) {
                #pragma unroll
                for (int r = 0; r < 4; ++r) {
                    const int row = row0 + wr * 64 + m * 16 + fq * 4 + r;
                    if (row >= Nr) continue;
                    const float v = acc[m][n][r];
                    if (to_z) Z16[(size_t)row * ld16 + oc] = f2h(v);
                    else      C1[(size_t)row * ld1 + oc] = v;
                }
            }
        }
    }
}

// ---------------------------------------------------------------------------
// CSR build: histogram, single-block scan, fill
// ---------------------------------------------------------------------------
__global__ void k_hist(const int* __restrict__ dst, int E, int* __restrict__ cnt)
{
    const int e = blockIdx.x * blockDim.x + threadIdx.x;
    if (e < E) atomicAdd(&cnt[dst[e]], 1);
}

__global__ __launch_bounds__(256) void k_scan(const int* __restrict__ cnt,
                                              int* __restrict__ rs, int n)
{
    __shared__ int sums[256];
    const int tid = threadIdx.x;
    const int T = (n + 255) / 256;
    const int base = tid * T;
    int s = 0;
    for (int i = 0; i < T; ++i) { const int idx = base + i; if (idx < n) s += cnt[idx]; }
    sums[tid] = s;
    __syncthreads();
    for (int o = 1; o < 256; o <<= 1) {
        const int v = (tid >= o) ? sums[tid - o] : 0;
        __syncthreads();
        sums[tid] += v;
        __syncthreads();
    }
    int run = (tid == 0) ? 0 : sums[tid - 1];
    for (int i = 0; i < T; ++i) {
        const int idx = base + i;
        if (idx < n) { rs[idx] = run; run += cnt[idx]; }
    }
    if (tid == 255) rs[n] = sums[255];
}

__global__ void k_fill(const int* __restrict__ src, const int* __restrict__ dst,
                       const float* __restrict__ ew, int E,
                       const int* __restrict__ rs, int* __restrict__ cur,
                       int* __restrict__ csrc, float* __restrict__ cew0,
                       float* __restrict__ cew1)
{
    const int e = blockIdx.x * blockDim.x + threadIdx.x;
    if (e >= E) return;
    const int d = dst[e];
    const int pos = rs[d] + atomicAdd(&cur[d], 1);
    csrc[pos] = src[e];
    cew0[pos] = ew[2 * e];
    cew1[pos] = ew[2 * e + 1];
}

// ---------------------------------------------------------------------------
// za_src / za_dst projections from fp16 z (row stride ldz), one wave per node
// ---------------------------------------------------------------------------
__global__ __launch_bounds__(256) void k_dotwa(
    const ushort_t* __restrict__ Z16, int ldz,
    const float* __restrict__ wa, int K, int N,
    float* __restrict__ za_s, float* __restrict__ za_d)
{
    const int lane = threadIdx.x & 63;
    const int node = blockIdx.x * 4 + (threadIdx.x >> 6);
    if (node >= N) return;
    const ushort_t* zr = Z16 + (size_t)node * ldz;
    float s = 0.f, d = 0.f;
    for (int k = lane; k < K; k += 64) {
        const float zv = h2f(zr[k]);
        s += zv * wa[k];
        d += zv * wa[K + k];
    }
    #pragma unroll
    for (int o = 32; o; o >>= 1) { s += __shfl_xor(s, o); d += __shfl_xor(d, o); }
    if (lane == 0) { za_s[node] = s; za_d[node] = d; }
}

__global__ __launch_bounds__(256) void k_wasums(const float* __restrict__ wa,
                                                int out, float* __restrict__ sums)
{
    __shared__ float red[256];
    const int tid = threadIdx.x;
    const int half = out >> 1;
    const float* t0 = wa + 2 * out;
    float s0 = 0.f, s1 = 0.f;
    for (int i = tid; i < half; i += 256) { s0 += t0[i]; s1 += t0[half + i]; }
    red[tid] = s0; __syncthreads();
    for (int o = 128; o; o >>= 1) { if (tid < o) red[tid] += red[tid + o]; __syncthreads(); }
    if (tid == 0) sums[0] = red[0];
    __syncthreads();
    red[tid] = s1; __syncthreads();
    for (int o = 128; o; o >>= 1) { if (tid < o) red[tid] += red[tid + o]; __syncthreads(); }
    if (tid == 0) sums[1] = red[0];
}

// ---------------------------------------------------------------------------
// per-dst edge softmax over CSR segment
// ---------------------------------------------------------------------------
__global__ __launch_bounds__(256) void k_attn(
    const int* __restrict__ rs, const int* __restrict__ csrc,
    const float* __restrict__ cew0, const float* __restrict__ cew1,
    const float* __restrict__ za_s, const float* __restrict__ za_d,
    const float* __restrict__ ewsums, float* __restrict__ EV, int N)
{
    const int lane = threadIdx.x & 63;
    const int n = blockIdx.x * 4 + (threadIdx.x >> 6);
    if (n >= N) return;
    const int s0 = rs[n];
    const int cnt = rs[n + 1] - s0;
    if (cnt == 0) return;
    const float zd = za_d[n];
    float w0 = 0.f, w1 = 0.f;
    if (ewsums) { w0 = ewsums[0]; w1 = ewsums[1]; }

    float mx = -INFINITY;
    for (int i = lane; i < cnt; i += 64) {
        float ev = za_s[csrc[s0 + i]] + zd + cew0[s0 + i] * w0 + cew1[s0 + i] * w1;
        ev = ev >= 0.f ? ev : 0.01f * ev;
        EV[s0 + i] = ev;
        mx = fmaxf(mx, ev);
    }
    #pragma unroll
    for (int o = 32; o; o >>= 1) mx = fmaxf(mx, __shfl_xor(mx, o));

    float sum = 0.f;
    for (int i = lane; i < cnt; i += 64) {
        const float ex = expf(EV[s0 + i] - mx);
        EV[s0 + i] = ex;
        sum += ex;
    }
    #pragma unroll
    for (int o = 32; o; o >>= 1) sum += __shfl_xor(sum, o);

    for (int i = lane; i < cnt; i += 64) EV[s0 + i] /= sum;
}

// ---------------------------------------------------------------------------
// aggregate + GAT epilogue. fp16 Z gather (stride ldz), HS stride ldh,
// Hin stride ldi. one wave per (node, 128-feature chunk).
// ---------------------------------------------------------------------------
__global__ __launch_bounds__(256) void k_aggfin(
    const int* __restrict__ rs, const int* __restrict__ csrc,
    const float* __restrict__ EV, const ushort_t* __restrict__ Z16, int ldz,
    const float* __restrict__ HS, int ldh,
    const float* __restrict__ Hin, int ldi,
    float* __restrict__ Out, int N, int out, int ldo, int coff)
{
    const int lane = threadIdx.x & 63;
    const int n = blockIdx.x * 4 + (threadIdx.x >> 6);
    if (n >= N) return;
    const int f = blockIdx.y * 128 + lane * 2;
    if (f >= out) return;
    const int s0 = rs[n];
    const int cnt = rs[n + 1] - s0;

    float ax = 0.f, ay = 0.f, bx = 0.f, by = 0.f;
    int i = 0;
    for (; i + 2 <= cnt; i += 2) {
        const int sn0 = csrc[s0 + i];
        const int sn1 = csrc[s0 + i + 1];
        const float w0 = EV[s0 + i];
        const float w1 = EV[s0 + i + 1];
        union { unsigned u; __half2 h; } c0, c1;
        c0.u = *reinterpret_cast<const unsigned*>(&Z16[(size_t)sn0 * ldz + f]);
        c1.u = *reinterpret_cast<const unsigned*>(&Z16[(size_t)sn1 * ldz + f]);
        const float2 z0 = __half22float2(c0.h);
        const float2 z1 = __half22float2(c1.h);
        ax += w0 * z0.x; ay += w0 * z0.y;
        bx += w1 * z1.x; by += w1 * z1.y;
    }
    if (i < cnt) {
        const int sn0 = csrc[s0 + i];
        const float w0 = EV[s0 + i];
        union { unsigned u; __half2 h; } c0;
        c0.u = *reinterpret_cast<const unsigned*>(&Z16[(size_t)sn0 * ldz + f]);
        const float2 z0 = __half22float2(c0.h);
        ax += w0 * z0.x; ay += w0 * z0.y;
    }
    const float accx = ax + bx, accy = ay + by;

    const float2 hv = *reinterpret_cast<const float2*>(&Hin[(size_t)n * ldi + f]);
    const float2 hs = *reinterpret_cast<const float2*>(&HS[(size_t)n * ldh + f]);
    const float hnx = (cnt > 0) ? (hs.x + accx) : hv.x;
    const float hny = (cnt > 0) ? (hs.y + accy) : hv.y;
    float2 o;
    o.x = hv.x + fmaxf(hnx, 0.f);
    o.y = hv.y + fmaxf(hny, 0.f);
    *reinterpret_cast<float2*>(&Out[(size_t)n * ldo + coff + f]) = o;
}

// ---------------------------------------------------------------------------
// column-block copy (float4)
// ---------------------------------------------------------------------------
__global__ void k_copy4(const float* __restrict__ src, int s_ld,
                        float* __restrict__ dst, int d_ld, int d_off,
                        int cols, int N)
{
    const int q = cols >> 2;
    const int idx = blockIdx.x * blockDim.x + threadIdx.x;
    if (idx >= N * q) return;
    const int r = idx / q;
    const int c = (idx % q) << 2;
    *reinterpret_cast<float4*>(&dst[(size_t)r * d_ld + d_off + c]) =
        *reinterpret_cast<const float4*>(&src[(size_t)r * s_ld + c]);
}

__global__ void k_reparam(const float* __restrict__ mu, const float* __restrict__ lv,
                          const float* __restrict__ eps, float* __restrict__ z, int total)
{
    const int i = blockIdx.x * blockDim.x + threadIdx.x;
    if (i < total) z[i] = mu[i] + expf(0.5f * lv[i]) * eps[i];
}

// ---------------------------------------------------------------------------
// host side
// ---------------------------------------------------------------------------
static inline void split_mat(hipStream_t st, const float* src, int R, int K, int Kp,
                             ushort_t* oh, ushort_t* ol, int row_off)
{
    const int total = R * (Kp >> 2);
    k_split<<<(total + 255) / 256, 256, 0, st>>>(src, R, K, Kp, oh, ol, row_off);
}

static inline void mgemm(hipStream_t st,
                         const ushort_t* Ah, const ushort_t* Al,
                         const ushort_t* Wh, const ushort_t* Wl,
                         const float* b0, const float* b1,
                         float* C0, int ld0, int M1, float* C1, int ld1,
                         ushort_t* Z16, int ld16,
                         int Nr, int Kp, int Mc, int act, float slope, int mode)
{
    dim3 g((Mc + 127) / 128, (Nr + 127) / 128);
    k_mgemm<<<g, 256, 0, st>>>(Ah, Al, Wh, Wl, b0, b1, C0, ld0, M1, C1, ld1,
                               Z16, ld16, Nr, Kp, Mc, act, slope, mode);
}

struct CsrPtrs {
    const int* rs; const int* csrc; const float* cew0; const float* cew1;
};

// nheads=1 or 2; weights/Wa arrays per head; Hin stride = dim for all uses here
static void gat_layer(hipStream_t st, const float* Hin, int dim, int Kp, int nheads,
                      const ushort_t* Ah, const ushort_t* Al,
                      const float* const* Ws, const float* const* Wf,
                      const float* const* Wa, bool has_ew,
                      ushort_t* Wh, ushort_t* Wl,
                      ushort_t* Z16, float* HSb,
                      float* za_s, float* za_d, float* wa_sums,
                      const CsrPtrs& csr, float* EV, float* Out, int ldo)
{
    // stack [Wf0; Ws0; (Wf1; Ws1)] row-wise
    for (int h = 0; h < nheads; ++h) {
        split_mat(st, Wf[h], dim, dim, Kp, Wh, Wl, (2 * h) * dim);
        split_mat(st, Ws[h], dim, dim, Kp, Wh, Wl, (2 * h + 1) * dim);
    }
    const int ldz = nheads * dim;
    mgemm(st, Ah, Al, Wh, Wl, nullptr, nullptr,
          nullptr, 0, dim, HSb, ldz, Z16, ldz,
          N_NODES, Kp, 2 * nheads * dim, 0, 0.f, 1);
    for (int h = 0; h < nheads; ++h) {
        k_dotwa<<<N_NODES / 4, 256, 0, st>>>(Z16 + h * dim, ldz, Wa[h], dim,
                                             N_NODES, za_s, za_d);
        const float* es = nullptr;
        if (has_ew) {
            k_wasums<<<1, 256, 0, st>>>(Wa[h], dim, wa_sums);
            es = wa_sums;
        }
        k_attn<<<N_NODES / 4, 256, 0, st>>>(csr.rs, csr.csrc, csr.cew0, csr.cew1,
                                            za_s, za_d, es, EV, N_NODES);
        dim3 ga(N_NODES / 4, (dim + 127) / 128);
        k_aggfin<<<ga, 256, 0, st>>>(csr.rs, csr.csrc, EV,
                                     Z16 + h * dim, ldz, HSb + h * dim, ldz,
                                     Hin, dim, Out, N_NODES, dim, ldo, h * dim);
    }
}

static inline void copy4(hipStream_t st, const float* src, int s_ld,
                         float* dst, int d_ld, int d_off, int cols)
{
    const int total = N_NODES * (cols >> 2);
    k_copy4<<<(total + 255) / 256, 256, 0, st>>>(src, s_ld, dst, d_ld, d_off, cols, N_NODES);
}

extern "C" void kernel_launch(void* const* d_in, const int* in_sizes, int n_in,
                              void* d_out, int out_size, void* d_ws, size_t ws_size,
                              hipStream_t stream)
{
    const float* feats    = (const float*)d_in[0];
    const float* gt       = (const float*)d_in[1];
    const float* maps_emb = (const float*)d_in[2];
    const float* e_w      = (const float*)d_in[3];
    const float* eps      = (const float*)d_in[4];
    const int*   src      = (const int*)d_in[5];
    const int*   dst      = (const int*)d_in[6];
    const float* emb_W    = (const float*)d_in[7];
    const float* emb_b    = (const float*)d_in[8];
    const float* enc1_Ws  = (const float*)d_in[9];
    const float* enc1_Wf  = (const float*)d_in[10];
    const float* enc1_Wa  = (const float*)d_in[11];
    const float* enc2_Ws  = (const float*)d_in[12];
    const float* enc2_Wf  = (const float*)d_in[13];
    const float* enc2_Wa  = (const float*)d_in[14];
    const float* encmlp_W = (const float*)d_in[15];
    const float* encmlp_b = (const float*)d_in[16];
    const float* mu_W     = (const float*)d_in[17];
    const float* mu_b     = (const float*)d_in[18];
    const float* lv_W     = (const float*)d_in[19];
    const float* lv_b     = (const float*)d_in[20];
    const float* dec1_Ws  = (const float*)d_in[21];
    const float* dec1_Wf  = (const float*)d_in[22];
    const float* dec1_Wa  = (const float*)d_in[23];
    const float* dec2_Ws  = (const float*)d_in[24];
    const float* dec2_Wf  = (const float*)d_in[25];
    const float* dec2_Wa  = (const float*)d_in[26];
    const float* dec0_W   = (const float*)d_in[27];
    const float* dec0_b   = (const float*)d_in[28];
    const float* dec1o_W  = (const float*)d_in[29];
    const float* dec1o_b  = (const float*)d_in[30];

    char* wp = (char*)d_ws;
    size_t off = 0;
    auto alloc_f = [&](size_t nf) -> float* {
        float* p = (float*)(wp + off);
        off = (off + nf * sizeof(float) + 255) & ~(size_t)255;
        return p;
    };
    auto alloc_i = [&](size_t ni) -> int* {
        int* p = (int*)(wp + off);
        off = (off + ni * sizeof(int) + 255) & ~(size_t)255;
        return p;
    };
    auto alloc_u = [&](size_t nu) -> ushort_t* {
        ushort_t* p = (ushort_t*)(wp + off);
        off = (off + nu * sizeof(ushort_t) + 255) & ~(size_t)255;
        return p;
    };

    // total ~245 MB (known-good R6 footprint)
    float* A_CAT   = alloc_f((size_t)N_NODES * 1088);
    float* OUTB    = alloc_f((size_t)N_NODES * 1120);
    float* Zb      = alloc_f((size_t)N_NODES * 548);   // MLP intermediates only
    float* HSb     = alloc_f((size_t)N_NODES * 1088);
    float* h_emb   = alloc_f((size_t)N_NODES * 256);
    float* zlat    = alloc_f((size_t)N_NODES * 32);
    float* za_s    = alloc_f(N_NODES);
    float* za_d    = alloc_f(N_NODES);
    float* EV      = alloc_f(N_EDGES);
    float* cew0    = alloc_f(N_EDGES);
    float* cew1    = alloc_f(N_EDGES);
    float* wa_sums = alloc_f(64);
    int*   cnt     = alloc_i(N_NODES);
    int*   rs      = alloc_i(N_NODES + 1);
    int*   csrc    = alloc_i(N_EDGES);
    ushort_t* Ah   = alloc_u((size_t)N_NODES * 1152);
    ushort_t* Al   = alloc_u((size_t)N_NODES * 1152);
    ushort_t* Wh   = alloc_u((size_t)2176 * 1088);
    ushort_t* Wl   = alloc_u((size_t)2176 * 1088);
    ushort_t* Z16  = alloc_u((size_t)N_NODES * 1088);
    (void)ws_size; (void)in_sizes; (void)n_in; (void)out_size;

    CsrPtrs csr{rs, csrc, cew0, cew1};

    // ---- CSR build ----
    hipMemsetAsync(cnt, 0, N_NODES * sizeof(int), stream);
    k_hist<<<(N_EDGES + 255) / 256, 256, 0, stream>>>(dst, N_EDGES, cnt);
    k_scan<<<1, 256, 0, stream>>>(cnt, rs, N_NODES);
    hipMemsetAsync(cnt, 0, N_NODES * sizeof(int), stream);
    k_fill<<<(N_EDGES + 255) / 256, 256, 0, stream>>>(src, dst, e_w, N_EDGES,
                                                      rs, cnt, csrc, cew0, cew1);

    // ---- embedding: h_emb = feats @ emb_W^T + emb_b ----
    split_mat(stream, feats, N_NODES, 24, 64, Ah, Al, 0);
    split_mat(stream, emb_W, 256, 24, 64, Wh, Wl, 0);
    mgemm(stream, Ah, Al, Wh, Wl, emb_b, nullptr,
          h_emb, 256, 256, h_emb, 256, nullptr, 0, N_NODES, 64, 256, 0, 0.f, 0);

    // ---- encoder input [maps_emb | h_emb | gt] (536) ----
    copy4(stream, maps_emb, 256, A_CAT, 536, 0, 256);
    copy4(stream, h_emb, 256, A_CAT, 536, 256, 256);
    copy4(stream, gt, 24, A_CAT, 536, 512, 24);

    // ---- encoder GAT layer 1 (2 heads merged, att_ew) -> OUTB [N,1072] ----
    split_mat(stream, A_CAT, N_NODES, 536, 576, Ah, Al, 0);
    {
        const float* Wsv[2] = {enc1_Ws, enc1_Ws + 536 * 536};
        const float* Wfv[2] = {enc1_Wf, enc1_Wf + 536 * 536};
        const float* Wav[2] = {enc1_Wa, enc1_Wa + 3 * 536};
        gat_layer(stream, A_CAT, 536, 576, 2, Ah, Al, Wsv, Wfv, Wav, true,
                  Wh, Wl, Z16, HSb, za_s, za_d, wa_sums, csr, EV, OUTB, 1072);
    }

    // ---- encoder GAT layer 2 (1 head, att_ew) -> A_CAT [N,1072] ----
    split_mat(stream, OUTB, N_NODES, 1072, 1088, Ah, Al, 0);
    {
        const float* Wsv[1] = {enc2_Ws};
        const float* Wfv[1] = {enc2_Wf};
        const float* Wav[1] = {enc2_Wa};
        gat_layer(stream, OUTB, 1072, 1088, 1, Ah, Al, Wsv, Wfv, Wav, true,
                  Wh, Wl, Z16, HSb, za_s, za_d, wa_sums, csr, EV, A_CAT, 1072);
    }

    // ---- MLP encoder + reparameterize ----
    copy4(stream, A_CAT, 1072, OUTB, 1096, 0, 1072);
    copy4(stream, gt, 24, OUTB, 1096, 1072, 24);
    split_mat(stream, OUTB, N_NODES, 1096, 1152, Ah, Al, 0);
    split_mat(stream, encmlp_W, 548, 1096, 1152, Wh, Wl, 0);
    mgemm(stream, Ah, Al, Wh, Wl, encmlp_b, nullptr,
          Zb, 548, 548, Zb, 548, nullptr, 0, N_NODES, 1152, 548, 1, 0.01f, 0);
    float* mu = HSb;
    float* lv = HSb + (size_t)N_NODES * 32;
    split_mat(stream, Zb, N_NODES, 548, 576, Ah, Al, 0);
    split_mat(stream, mu_W, 32, 548, 576, Wh, Wl, 0);
    split_mat(stream, lv_W, 32, 548, 576, Wh, Wl, 32);
    mgemm(stream, Ah, Al, Wh, Wl, mu_b, lv_b,
          mu, 32, 32, lv, 32, nullptr, 0, N_NODES, 576, 64, 0, 0.f, 0);
    k_reparam<<<(N_NODES * 32 + 255) / 256, 256, 0, stream>>>(mu, lv, eps, zlat,
                                                              N_NODES * 32);

    // ---- decoder input [maps_emb | h_emb | z] (544) ----
    copy4(stream, maps_emb, 256, A_CAT, 544, 0, 256);
    copy4(stream, h_emb, 256, A_CAT, 544, 256, 256);
    copy4(stream, zlat, 32, A_CAT, 544, 512, 32);

    // ---- decoder GAT layer 1 (2 heads merged) -> OUTB [N,1088] ----
    split_mat(stream, A_CAT, N_NODES, 544, 576, Ah, Al, 0);
    {
        const float* Wsv[2] = {dec1_Ws, dec1_Ws + 544 * 544};
        const float* Wfv[2] = {dec1_Wf, dec1_Wf + 544 * 544};
        const float* Wav[2] = {dec1_Wa, dec1_Wa + 2 * 544};
        gat_layer(stream, A_CAT, 544, 576, 2, Ah, Al, Wsv, Wfv, Wav, false,
                  Wh, Wl, Z16, HSb, za_s, za_d, wa_sums, csr, EV, OUTB, 1088);
    }

    // ---- decoder GAT layer 2 (1 head) -> A_CAT [N,1088] ----
    split_mat(stream, OUTB, N_NODES, 1088, 1088, Ah, Al, 0);
    {
        const float* Wsv[1] = {dec2_Ws};
        const float* Wfv[1] = {dec2_Wf};
        const float* Wav[1] = {dec2_Wa};
        gat_layer(stream, OUTB, 1088, 1088, 1, Ah, Al, Wsv, Wfv, Wav, false,
                  Wh, Wl, Z16, HSb, za_s, za_d, wa_sums, csr, EV, A_CAT, 1088);
    }

    // ---- MLP decoder ----
    copy4(stream, A_CAT, 1088, OUTB, 1120, 0, 1088);
    copy4(stream, zlat, 32, OUTB, 1120, 1088, 32);
    split_mat(stream, OUTB, N_NODES, 1120, 1152, Ah, Al, 0);
    split_mat(stream, dec0_W, 544, 1120, 1152, Wh, Wl, 0);
    mgemm(stream, Ah, Al, Wh, Wl, dec0_b, nullptr,
          Zb, 544, 544, Zb, 544, nullptr, 0, N_NODES, 1152, 544, 1, 0.02f, 0);
    split_mat(stream, Zb, N_NODES, 544, 576, Ah, Al, 0);
    split_mat(stream, dec1o_W, 24, 544, 576, Wh, Wl, 0);
    mgemm(stream, Ah, Al, Wh, Wl, dec1o_b, nullptr,
          (float*)d_out, 24, 24, (float*)d_out, 24, nullptr, 0, N_NODES, 576, 24, 0, 0.f, 0);
}